// Round 10
// baseline (700.205 us; speedup 1.0000x reference)
//
#include <hip/hip_runtime.h>
#include <stdint.h>

#define M_TOK 2048
#define HID   1024
#define NEXP  64
#define TOPK  6
#define TOTSLOT (M_TOK*TOPK)   // 12288

typedef unsigned short u16;
typedef __attribute__((ext_vector_type(4))) u16   u16x4;
typedef __attribute__((ext_vector_type(8))) u16   u16x8;
typedef __attribute__((ext_vector_type(4))) float f32x4;
typedef __attribute__((ext_vector_type(8))) short bf16x8;

__device__ __forceinline__ u16 f2b(float f) {
    union { float f; uint32_t u; } v; v.f = f;
    uint32_t r = v.u + 0x7FFFu + ((v.u >> 16) & 1u);
    return (u16)(r >> 16);
}
__device__ __forceinline__ float b2f(u16 b) {
    union { uint32_t u; float f; } v; v.u = ((uint32_t)b) << 16; return v.f;
}

// ---------------- x fp32 -> bf16 ----------------
__global__ __launch_bounds__(256) void convert_x_kernel(const float* __restrict__ x,
                                                        u16* __restrict__ xb) {
    int i = (blockIdx.x * 256 + threadIdx.x) * 4;
    float4 v = *reinterpret_cast<const float4*>(x + i);
    u16x4 o; o[0] = f2b(v.x); o[1] = f2b(v.y); o[2] = f2b(v.z); o[3] = f2b(v.w);
    *reinterpret_cast<u16x4*>(xb + i) = o;
}

// ---------------- gw transpose: gwT[k][e] so router lanes read coalesced ----------------
__global__ __launch_bounds__(256) void transpose_gw_kernel(const float* __restrict__ gw,
                                                           float* __restrict__ gwT) {
    int i = blockIdx.x * 256 + threadIdx.x;   // 65536 elements
    int e = i >> 10, k = i & 1023;
    gwT[k * NEXP + e] = gw[i];
}

// ---------------- router: fp64 logits (coalesced gwT), grouped topk ----------------
__global__ __launch_bounds__(64) void router_kernel(
    const float* __restrict__ x, const float* __restrict__ gwT,
    int* __restrict__ topk_id, float* __restrict__ topk_w, int* __restrict__ counts)
{
    int t = blockIdx.x, lane = threadIdx.x;
    __shared__ float xr[HID];
    for (int k = lane; k < HID; k += 64) xr[k] = x[(size_t)t * HID + k];
    __syncthreads();
    double s0 = 0.0, s1 = 0.0, s2 = 0.0, s3 = 0.0;
    for (int k = 0; k < HID; k += 4) {
        s0 += (double)xr[k]   * (double)gwT[(k)   * NEXP + lane];
        s1 += (double)xr[k+1] * (double)gwT[(k+1) * NEXP + lane];
        s2 += (double)xr[k+2] * (double)gwT[(k+2) * NEXP + lane];
        s3 += (double)xr[k+3] * (double)gwT[(k+3) * NEXP + lane];
    }
    double s = (s0 + s1) + (s2 + s3);
    __shared__ double lg[NEXP];
    __shared__ float  pr[NEXP];
    float sf = (float)s;
    float mx = sf;
    for (int o = 32; o; o >>= 1) mx = fmaxf(mx, __shfl_xor(mx, o));
    float ev = __expf(sf - mx);
    float sum = ev;
    for (int o = 32; o; o >>= 1) sum += __shfl_xor(sum, o);
    lg[lane] = s; pr[lane] = ev / sum;
    __syncthreads();
    if (lane == 0) {
        double gs[8];
        #pragma unroll
        for (int g = 0; g < 8; ++g) {
            double m = lg[g*8];
            #pragma unroll
            for (int i = 1; i < 8; ++i) m = fmax(m, lg[g*8+i]);
            gs[g] = m;
        }
        unsigned gsel = 0;
        for (int r = 0; r < 3; ++r) {
            int bi = 0; double bv = -1e300;
            for (int g = 0; g < 8; ++g)
                if (!((gsel>>g)&1u) && gs[g] > bv) { bv = gs[g]; bi = g; }
            gsel |= 1u << bi;
        }
        unsigned long long taken = 0;
        for (int r = 0; r < TOPK; ++r) {
            int bi = 0; double bv = -1e300;
            for (int e = 0; e < NEXP; ++e) {
                if (!((gsel >> (e>>3)) & 1u)) continue;
                if ((taken >> e) & 1ull) continue;
                if (lg[e] > bv) { bv = lg[e]; bi = e; }
            }
            taken |= 1ull << bi;
            topk_id[t*TOPK + r] = bi;
            topk_w[t*TOPK + r] = pr[bi];
            atomicAdd(&counts[bi], 1);
        }
    }
}

__global__ void scan_kernel(const int* __restrict__ counts, int* __restrict__ offs,
                            int* __restrict__ cursor) {
    if (threadIdx.x == 0) {
        int acc = 0;
        for (int e = 0; e < NEXP; ++e) { offs[e] = acc; cursor[e] = acc; acc += counts[e]; }
        offs[NEXP] = acc;
    }
}

__global__ __launch_bounds__(256) void fill_kernel(
    const int* __restrict__ topk_id, const float* __restrict__ topk_w,
    int* __restrict__ cursor, int* __restrict__ stok, float* __restrict__ sw,
    int* __restrict__ spos)
{
    int idx = blockIdx.x*256 + threadIdx.x;
    if (idx >= TOTSLOT) return;
    int e = topk_id[idx];
    int pos = atomicAdd(&cursor[e], 1);
    stok[pos] = idx / TOPK;
    sw[pos] = topk_w[idx];
    spos[idx] = pos;
}

// ---------------- routed MFMA GEMM: B full-K resident in LDS (sequential HBM read) ----
// KIND 0: gate/up  A=xb[token] K=1024, B=w1[e] rows {nblk*32 gate, 1024+nblk*32 up} -> h
// KIND 2: down     A=h        K=1024, B=w2[e] rows nblk*64..+63                     -> y
// BM=224 (7 waves x 32 rows), BN=64. B bulk-loaded ONCE per block as one (two) fully
// contiguous 128KB fp32 chunks -> f2b -> LDS (XOR p^(row&7) chunk swizzle). K-loop has
// zero B traffic; A double-buffered via global_load_lds (R7-verified addressing).
template<int KIND>
__global__ __launch_bounds__(448, 2) void gemm_routed(
    const u16* __restrict__ A, const float* __restrict__ Bw,
    u16* __restrict__ Hout,
    const int* __restrict__ offs, const int* __restrict__ stok,
    const float* __restrict__ sw)
{
    constexpr int BM    = 224;
    constexpr int KD    = 1024;
    constexpr int KITER = 32;

    __shared__ u16 As[2][BM*32];   // 28672 B
    __shared__ u16 Bs[64*1024];    // 131072 B  (total 159744 < 160 KiB)

    const int tid  = threadIdx.x;
    const int lane = tid & 63;
    const int wv   = tid >> 6;     // 0..6

    const int e   = blockIdx.z;
    const int off = offs[e];
    const int cnt = offs[e+1] - off;
    const int m0  = blockIdx.y * BM;
    if (m0 >= cnt) return;
    const int nblk = blockIdx.x;

    const float* Be = Bw + (size_t)e * (size_t)(KIND == 0 ? 2*1024*1024 : 1024*1024);

    // ---- bulk B: 64 rows x 1024 fp32, sequential read, bf16 convert, swizzled LDS ----
    for (int it = 0; it < 19; ++it) {
        int f8 = it*448 + tid;            // pair-of-float4 units (32 B), 8192 total
        if (f8 < 8192) {
            int row = f8 >> 7, p = f8 & 127;
            int srcRow;
            if (KIND == 0) srcRow = (row < 32) ? (nblk*32 + row) : (1024 + nblk*32 + (row - 32));
            else           srcRow = nblk*64 + row;
            const float* s = Be + (size_t)srcRow * 1024 + p*8;
            float4 v0 = *reinterpret_cast<const float4*>(s);
            float4 v1 = *reinterpret_cast<const float4*>(s + 4);
            u16x8 w;
            w[0]=f2b(v0.x); w[1]=f2b(v0.y); w[2]=f2b(v0.z); w[3]=f2b(v0.w);
            w[4]=f2b(v1.x); w[5]=f2b(v1.y); w[6]=f2b(v1.z); w[7]=f2b(v1.w);
            *reinterpret_cast<u16x8*>(&Bs[row*1024 + ((p ^ (row & 7)) * 8)]) = w;
        }
    }

    // ---- A staging (R7-verified): pre-swizzled source chunk, linear LDS dest ----
    const int acol8 = (lane & 3) ^ ((lane >> 3) & 3);
    int aoff[2];
    #pragma unroll
    for (int j = 0; j < 2; ++j) {
        int r = wv*32 + j*16 + (lane >> 2);
        int arow;
        if (KIND == 0) {
            arow = (m0 + r < cnt) ? stok[off + m0 + r] : 0;
        } else {
            int t = off + m0 + r; arow = (t < TOTSLOT) ? t : (TOTSLOT - 1);
        }
        aoff[j] = arow * KD + acol8 * 8;
    }
    auto stageA = [&](int buf, int k0) {
        #pragma unroll
        for (int j = 0; j < 2; ++j) {
            __builtin_amdgcn_global_load_lds(
                (const __attribute__((address_space(1))) uint32_t*)(A + (size_t)(aoff[j] + k0)),
                (__attribute__((address_space(3))) uint32_t*)(&As[buf][(wv*32 + j*16)*32]),
                16, 0, 0);
        }
    };

    f32x4 acc[2][4];
    #pragma unroll
    for (int mf = 0; mf < 2; ++mf)
        #pragma unroll
        for (int nf = 0; nf < 4; ++nf)
            acc[mf][nf] = (f32x4){0.f, 0.f, 0.f, 0.f};

    const int slot = lane >> 4;
    const int xoff = ((slot ^ (((lane & 15) >> 1) & 3)) << 4);

    stageA(0, 0);
    __syncthreads();   // B resident + A tile 0 resident

    for (int kt = 0; kt < KITER; ++kt) {
        const int cur = kt & 1, nxt = cur ^ 1;
        if (kt + 1 < KITER) stageA(nxt, (kt + 1) * 32);

        bf16x8 af[2];
        #pragma unroll
        for (int mf = 0; mf < 2; ++mf) {
            int row = wv*32 + mf*16 + (lane & 15);
            af[mf] = *reinterpret_cast<const bf16x8*>((const char*)&As[cur][0] + row*64 + xoff);
        }
        #pragma unroll
        for (int nf = 0; nf < 4; ++nf) {
            int browf = nf*16 + (lane & 15);
            int eff = (kt*4 + slot) ^ (browf & 7);
            bf16x8 bfr = *reinterpret_cast<const bf16x8*>(&Bs[browf*1024 + eff*8]);
            #pragma unroll
            for (int mf = 0; mf < 2; ++mf)
                acc[mf][nf] = __builtin_amdgcn_mfma_f32_16x16x32_bf16(af[mf], bfr, acc[mf][nf], 0, 0, 0);
        }
        __syncthreads();
    }

    // ---- epilogue ----
    #pragma unroll
    for (int mf = 0; mf < 2; ++mf) {
        #pragma unroll
        for (int j = 0; j < 4; ++j) {
            int r = wv*32 + mf*16 + (lane >> 4)*4 + j;
            if (m0 + r >= cnt) continue;
            size_t orow = (size_t)(off + m0 + r);
            if constexpr (KIND == 0) {
                float wgt = sw[off + m0 + r];
                #pragma unroll
                for (int nf = 0; nf < 2; ++nf) {
                    float g = acc[mf][nf][j];
                    float u = acc[mf][nf+2][j];
                    float hv = (g / (1.f + __expf(-g))) * u * wgt;
                    Hout[orow * 1024 + nblk*32 + nf*16 + (lane & 15)] = f2b(hv);
                }
            } else {
                #pragma unroll
                for (int nf = 0; nf < 4; ++nf)
                    Hout[orow * 1024 + nblk*64 + nf*16 + (lane & 15)] = f2b(acc[mf][nf][j]);
            }
        }
    }
}

// ---------------- shared-expert MFMA GEMM (R7 simple path) ----------------
// KIND 1: gate/up  BM=256 BN=128  A=xb K=1024, B=sgu -> hs (bf16)
// KIND 3: down     BM=128 BN=64   A=hs K=2048, B=sdn -> Out (f32)
template<int KIND>
__global__ __launch_bounds__(512, 4) void gemm_shared(
    const u16* __restrict__ A, const float* __restrict__ Bw,
    u16* __restrict__ Hout, float* __restrict__ Out)
{
    constexpr bool G1    = (KIND == 1);
    constexpr int  BM    = G1 ? 256 : 128;
    constexpr int  MR    = BM / 128;
    constexpr int  BN    = G1 ? 128 : 64;
    constexpr int  NF    = BN / 16;
    constexpr int  KD    = G1 ? 1024 : 2048;
    constexpr int  KITER = KD / 32;
    constexpr int  NPAIR = 2048;          // sgu up-row offset / hs stride
    constexpr int  TPR   = 512 / BN;
    constexpr int  CPT   = 32 / TPR;
    constexpr int  BREG  = CPT / 4;

    __shared__ u16 As[2][BM*32];
    __shared__ u16 Bs[2][BN*32];

    const int tid  = threadIdx.x;
    const int lane = tid & 63;
    const int wv   = tid >> 6;
    const int m0   = blockIdx.y * BM;
    const int nblk = blockIdx.x;

    const int acol8 = (lane & 3) ^ ((lane >> 3) & 3);
    int aoff[MR];
    #pragma unroll
    for (int j = 0; j < MR; ++j) {
        int r = wv*(16*MR) + j*16 + (lane >> 2);
        aoff[j] = (m0 + r) * KD + acol8 * 8;
    }

    const int rb = tid / TPR;
    const int q  = tid % TPR;
    int brow;
    if (G1) brow = (rb < 64) ? (nblk*64 + rb) : (NPAIR + nblk*64 + (rb - 64));
    else    brow = nblk*BN + rb;
    const float* bsrc = Bw + (size_t)brow * KD + q*CPT;

    auto stageA = [&](int buf, int k0) {
        #pragma unroll
        for (int j = 0; j < MR; ++j) {
            __builtin_amdgcn_global_load_lds(
                (const __attribute__((address_space(1))) uint32_t*)(A + (size_t)(aoff[j] + k0)),
                (__attribute__((address_space(3))) uint32_t*)(&As[buf][(wv*(16*MR) + j*16)*32]),
                16, 0, 0);
        }
    };
    float4 br[BREG];
    auto loadB = [&](int k0) {
        #pragma unroll
        for (int j = 0; j < BREG; ++j)
            br[j] = *reinterpret_cast<const float4*>(bsrc + k0 + j*4);
    };
    auto storeB = [&](int buf) {
        char* bd = (char*)&Bs[buf][0] + rb*64;
        if constexpr (CPT == 8) {
            u16x8 w;
            w[0] = f2b(br[0].x); w[1] = f2b(br[0].y); w[2] = f2b(br[0].z); w[3] = f2b(br[0].w);
            w[4] = f2b(br[1].x); w[5] = f2b(br[1].y); w[6] = f2b(br[1].z); w[7] = f2b(br[1].w);
            *reinterpret_cast<u16x8*>(bd + ((q ^ ((rb >> 1) & 3)) << 4)) = w;
        } else {
            u16x4 w;
            w[0] = f2b(br[0].x); w[1] = f2b(br[0].y); w[2] = f2b(br[0].z); w[3] = f2b(br[0].w);
            *reinterpret_cast<u16x4*>(bd + (((q>>1) ^ ((rb >> 1) & 3)) << 4) + (q & 1) * 8) = w;
        }
    };

    f32x4 acc[MR][NF];
    #pragma unroll
    for (int mf = 0; mf < MR; ++mf)
        #pragma unroll
        for (int nf = 0; nf < NF; ++nf)
            acc[mf][nf] = (f32x4){0.f, 0.f, 0.f, 0.f};

    const int slot = lane >> 4;
    const int xoff = ((slot ^ (((lane & 15) >> 1) & 3)) << 4);

    stageA(0, 0);
    loadB(0);
    storeB(0);
    __syncthreads();

    for (int kt = 0; kt < KITER; ++kt) {
        const int cur = kt & 1, nxt = cur ^ 1;
        const bool more = (kt + 1 < KITER);
        if (more) { stageA(nxt, (kt + 1) * 32); loadB((kt + 1) * 32); }

        bf16x8 af[MR];
        #pragma unroll
        for (int mf = 0; mf < MR; ++mf) {
            int row = wv*(16*MR) + mf*16 + (lane & 15);
            af[mf] = *reinterpret_cast<const bf16x8*>((const char*)&As[cur][0] + row*64 + xoff);
        }
        #pragma unroll
        for (int nf = 0; nf < NF; ++nf) {
            int rowb = nf*16 + (lane & 15);
            bf16x8 bfr = *reinterpret_cast<const bf16x8*>((const char*)&Bs[cur][0] + rowb*64 + xoff);
            #pragma unroll
            for (int mf = 0; mf < MR; ++mf)
                acc[mf][nf] = __builtin_amdgcn_mfma_f32_16x16x32_bf16(af[mf], bfr, acc[mf][nf], 0, 0, 0);
        }
        if (more) storeB(nxt);
        __syncthreads();
    }

    if constexpr (G1) {
        const int colbase = nblk*64 + (lane & 15);
        #pragma unroll
        for (int mf = 0; mf < MR; ++mf) {
            #pragma unroll
            for (int j = 0; j < 4; ++j) {
                int r = wv*(16*MR) + mf*16 + (lane >> 4)*4 + j;
                size_t orow = (size_t)(m0 + r);
                #pragma unroll
                for (int nf = 0; nf < 4; ++nf) {
                    float g = acc[mf][nf][j];
                    float u = acc[mf][nf+4][j];
                    float hv = (g / (1.f + __expf(-g))) * u;
                    Hout[orow * NPAIR + colbase + nf*16] = f2b(hv);
                }
            }
        }
    } else {
        const int colbase = nblk*BN + (lane & 15);
        #pragma unroll
        for (int mf = 0; mf < MR; ++mf) {
            #pragma unroll
            for (int j = 0; j < 4; ++j) {
                int r = wv*(16*MR) + mf*16 + (lane >> 4)*4 + j;
                #pragma unroll
                for (int nf = 0; nf < NF; ++nf)
                    Out[(size_t)(m0 + r) * HID + colbase + nf*16] = acc[mf][nf][j];
            }
        }
    }
}

// ---------------- gather-reduce: out[t] += sum_k y[spos[t,k]] ----------------
__global__ __launch_bounds__(256) void reduce_kernel(
    const u16* __restrict__ y, const int* __restrict__ spos, float* __restrict__ out)
{
    int t = blockIdx.x;
    int c = threadIdx.x * 4;
    float4 o = *reinterpret_cast<const float4*>(out + (size_t)t*HID + c);
    #pragma unroll
    for (int k = 0; k < TOPK; ++k) {
        int p = spos[t*TOPK + k];
        u16x4 v = *reinterpret_cast<const u16x4*>(y + (size_t)p*HID + c);
        o.x += b2f(v[0]); o.y += b2f(v[1]); o.z += b2f(v[2]); o.w += b2f(v[3]);
    }
    *reinterpret_cast<float4*>(out + (size_t)t*HID + c) = o;
}

extern "C" void kernel_launch(void* const* d_in, const int* in_sizes, int n_in,
                              void* d_out, int out_size, void* d_ws, size_t ws_size,
                              hipStream_t stream)
{
    const float* x   = (const float*)d_in[0];
    const float* gw  = (const float*)d_in[1];
    const float* w1  = (const float*)d_in[2];
    const float* w2  = (const float*)d_in[3];
    const float* sgu = (const float*)d_in[4];
    const float* sdn = (const float*)d_in[5];
    float* out = (float*)d_out;

    char* p = (char*)d_ws;
    auto carve = [&](size_t bytes) { char* r = p; p += (bytes + 255) & ~(size_t)255; return r; };
    u16*   xb      = (u16*)  carve((size_t)M_TOK * HID * 2);
    u16*   h       = (u16*)  carve((size_t)TOTSLOT * 1024 * 2);
    u16*   hs      = (u16*)  carve((size_t)M_TOK * 2048 * 2);
    u16*   y       = (u16*)  carve((size_t)TOTSLOT * HID * 2);
    float* gwT     = (float*)carve((size_t)HID * NEXP * 4);
    int*   topk_id = (int*)  carve(M_TOK * TOPK * 4);
    float* topk_w  = (float*)carve(M_TOK * TOPK * 4);
    int*   counts  = (int*)  carve(NEXP * 4);
    int*   offs    = (int*)  carve((NEXP + 1) * 4);
    int*   cursor  = (int*)  carve(NEXP * 4);
    int*   stok    = (int*)  carve(TOTSLOT * 4);
    float* sw      = (float*)carve(TOTSLOT * 4);
    int*   spos    = (int*)  carve(TOTSLOT * 4);

    hipMemsetAsync(counts, 0, NEXP * 4, stream);
    convert_x_kernel<<<(M_TOK*HID/4 + 255)/256, 256, 0, stream>>>(x, xb);
    transpose_gw_kernel<<<(NEXP*HID + 255)/256, 256, 0, stream>>>(gw, gwT);
    router_kernel<<<M_TOK, 64, 0, stream>>>(x, gwT, topk_id, topk_w, counts);
    scan_kernel<<<1, 64, 0, stream>>>(counts, offs, cursor);
    fill_kernel<<<(TOTSLOT + 255)/256, 256, 0, stream>>>(topk_id, topk_w, cursor, stok, sw, spos);

    // shared expert path (writes d_out fully), routed experts into y, then gather
    gemm_shared<1><<<dim3(32,8,1),  512, 0, stream>>>(xb, sgu, hs, nullptr);
    gemm_shared<3><<<dim3(16,16,1), 512, 0, stream>>>(hs, sdn, nullptr, out);
    gemm_routed<0><<<dim3(32,2,64), 448, 0, stream>>>(xb, w1, h, offs, stok, sw);
    gemm_routed<2><<<dim3(16,2,64), 448, 0, stream>>>(h,  w2, y, offs, stok, sw);
    reduce_kernel<<<M_TOK, 256, 0, stream>>>(y, spos, out);
}

// Round 11
// 698.885 us; speedup vs baseline: 1.0019x; 1.0019x over previous
//
#include <hip/hip_runtime.h>
#include <stdint.h>

#define M_TOK 2048
#define HID   1024
#define NEXP  64
#define TOPK  6
#define TOTSLOT (M_TOK*TOPK)   // 12288

typedef unsigned short u16;
typedef __attribute__((ext_vector_type(4))) u16   u16x4;
typedef __attribute__((ext_vector_type(8))) u16   u16x8;
typedef __attribute__((ext_vector_type(4))) float f32x4;
typedef __attribute__((ext_vector_type(8))) short bf16x8;

__device__ __forceinline__ u16 f2b(float f) {
    union { float f; uint32_t u; } v; v.f = f;
    uint32_t r = v.u + 0x7FFFu + ((v.u >> 16) & 1u);
    return (u16)(r >> 16);
}
__device__ __forceinline__ float b2f(u16 b) {
    union { uint32_t u; float f; } v; v.u = ((uint32_t)b) << 16; return v.f;
}

// ---------------- streaming fp32 -> bf16 (grid-stride, copy-class BW) ----------------
__global__ __launch_bounds__(256) void convert_w_kernel(const float* __restrict__ s,
                                                        u16* __restrict__ d, int n4) {
    int i = blockIdx.x * 256 + threadIdx.x;
    int stride = gridDim.x * 256;
    for (; i < n4; i += stride) {
        float4 v = *reinterpret_cast<const float4*>(s + (size_t)i * 4);
        u16x4 o; o[0] = f2b(v.x); o[1] = f2b(v.y); o[2] = f2b(v.z); o[3] = f2b(v.w);
        *reinterpret_cast<u16x4*>(d + (size_t)i * 4) = o;
    }
}

// ---------------- x fp32 -> bf16 ----------------
__global__ __launch_bounds__(256) void convert_x_kernel(const float* __restrict__ x,
                                                        u16* __restrict__ xb) {
    int i = (blockIdx.x * 256 + threadIdx.x) * 4;
    float4 v = *reinterpret_cast<const float4*>(x + i);
    u16x4 o; o[0] = f2b(v.x); o[1] = f2b(v.y); o[2] = f2b(v.z); o[3] = f2b(v.w);
    *reinterpret_cast<u16x4*>(xb + i) = o;
}

// ---------------- gw transpose: gwT[k][e] so router lanes read coalesced ----------------
__global__ __launch_bounds__(256) void transpose_gw_kernel(const float* __restrict__ gw,
                                                           float* __restrict__ gwT) {
    int i = blockIdx.x * 256 + threadIdx.x;   // 65536 elements
    int e = i >> 10, k = i & 1023;
    gwT[k * NEXP + e] = gw[i];
}

// ---------------- router: fp64 logits (coalesced gwT), grouped topk ----------------
__global__ __launch_bounds__(64) void router_kernel(
    const float* __restrict__ x, const float* __restrict__ gwT,
    int* __restrict__ topk_id, float* __restrict__ topk_w, int* __restrict__ counts)
{
    int t = blockIdx.x, lane = threadIdx.x;
    __shared__ float xr[HID];
    for (int k = lane; k < HID; k += 64) xr[k] = x[(size_t)t * HID + k];
    __syncthreads();
    double s0 = 0.0, s1 = 0.0, s2 = 0.0, s3 = 0.0;
    for (int k = 0; k < HID; k += 4) {
        s0 += (double)xr[k]   * (double)gwT[(k)   * NEXP + lane];
        s1 += (double)xr[k+1] * (double)gwT[(k+1) * NEXP + lane];
        s2 += (double)xr[k+2] * (double)gwT[(k+2) * NEXP + lane];
        s3 += (double)xr[k+3] * (double)gwT[(k+3) * NEXP + lane];
    }
    double s = (s0 + s1) + (s2 + s3);
    __shared__ double lg[NEXP];
    __shared__ float  pr[NEXP];
    float sf = (float)s;
    float mx = sf;
    for (int o = 32; o; o >>= 1) mx = fmaxf(mx, __shfl_xor(mx, o));
    float ev = __expf(sf - mx);
    float sum = ev;
    for (int o = 32; o; o >>= 1) sum += __shfl_xor(sum, o);
    lg[lane] = s; pr[lane] = ev / sum;
    __syncthreads();
    if (lane == 0) {
        double gs[8];
        #pragma unroll
        for (int g = 0; g < 8; ++g) {
            double m = lg[g*8];
            #pragma unroll
            for (int i = 1; i < 8; ++i) m = fmax(m, lg[g*8+i]);
            gs[g] = m;
        }
        unsigned gsel = 0;
        for (int r = 0; r < 3; ++r) {
            int bi = 0; double bv = -1e300;
            for (int g = 0; g < 8; ++g)
                if (!((gsel>>g)&1u) && gs[g] > bv) { bv = gs[g]; bi = g; }
            gsel |= 1u << bi;
        }
        unsigned long long taken = 0;
        for (int r = 0; r < TOPK; ++r) {
            int bi = 0; double bv = -1e300;
            for (int e = 0; e < NEXP; ++e) {
                if (!((gsel >> (e>>3)) & 1u)) continue;
                if ((taken >> e) & 1ull) continue;
                if (lg[e] > bv) { bv = lg[e]; bi = e; }
            }
            taken |= 1ull << bi;
            topk_id[t*TOPK + r] = bi;
            topk_w[t*TOPK + r] = pr[bi];
            atomicAdd(&counts[bi], 1);
        }
    }
}

__global__ void scan_kernel(const int* __restrict__ counts, int* __restrict__ offs,
                            int* __restrict__ cursor) {
    if (threadIdx.x == 0) {
        int acc = 0;
        for (int e = 0; e < NEXP; ++e) { offs[e] = acc; cursor[e] = acc; acc += counts[e]; }
        offs[NEXP] = acc;
    }
}

__global__ __launch_bounds__(256) void fill_kernel(
    const int* __restrict__ topk_id, const float* __restrict__ topk_w,
    int* __restrict__ cursor, int* __restrict__ stok, float* __restrict__ sw,
    int* __restrict__ spos)
{
    int idx = blockIdx.x*256 + threadIdx.x;
    if (idx >= TOTSLOT) return;
    int e = topk_id[idx];
    int pos = atomicAdd(&cursor[e], 1);
    stok[pos] = idx / TOPK;
    sw[pos] = topk_w[idx];
    spos[idx] = pos;
}

// ================= PATH A: bf16 weights, dual global_load_lds staging =================
// KIND 0: routed gate/up  BN=128  A=xb[tok] K=1024, B=w1b[e] -> h (silu*up*w, bf16)
// KIND 1: shared gate/up  BN=128  A=xb      K=1024, B=sgub   -> hs (bf16)
// KIND 2: routed down     BN=128  A=h       K=1024, B=w2b[e] -> y  (bf16)
// KIND 3: shared down     BN=64   A=hs      K=2048, B=sdnb   -> Out (f32)
// BM=256, BK=32, 512 thr (8 waves x 32 rows x BN). No data-VGPRs in the staging path.
template<int KIND>
__global__ __launch_bounds__(512, 4) void gemm_bf16(
    const u16* __restrict__ A, const u16* __restrict__ Bb,
    u16* __restrict__ Hout, float* __restrict__ Out,
    const int* __restrict__ offs, const int* __restrict__ stok,
    const float* __restrict__ sw)
{
    constexpr bool G1     = (KIND == 0 || KIND == 1);
    constexpr bool ROUTED = (KIND == 0 || KIND == 2);
    constexpr int  BM     = 256;
    constexpr int  BN     = (KIND == 3) ? 64 : 128;
    constexpr int  NF     = BN / 16;
    constexpr int  KD     = (KIND == 3) ? 2048 : 1024;
    constexpr int  KITER  = KD / 32;
    constexpr int  NPAIR  = (KIND == 0) ? 1024 : 2048;
    constexpr int  BWG    = BN / 16;      // B wave-groups (8 or 4)

    __shared__ u16 As[2][BM*32];          // 32 KB
    __shared__ u16 Bs[2][BN*32];          // 16 KB (8 KB kind 3)
    __shared__ int   tkl[ROUTED ? BM : 1];
    __shared__ float swl[(KIND == 0) ? BM : 1];

    const int tid  = threadIdx.x;
    const int lane = tid & 63;
    const int wv   = tid >> 6;

    const int e = ROUTED ? blockIdx.z : 0;
    int off = 0, cnt = M_TOK;
    if (ROUTED) { off = offs[e]; cnt = offs[e+1] - off; }
    const int m0 = blockIdx.y * BM;
    if (m0 >= cnt) return;
    const int nblk = blockIdx.x;

    if (ROUTED && tid < BM) {
        int gr = m0 + tid;
        if (KIND == 0) {
            tkl[tid] = (gr < cnt) ? stok[off + gr] : 0;
            swl[tid] = (gr < cnt) ? sw[off + gr] : 0.f;
        } else {
            int r = off + gr; if (r > TOTSLOT-1) r = TOTSLOT-1;
            tkl[tid] = r;
        }
    }
    __syncthreads();

    // A staging (R7-verified): pre-swizzled source chunk, linear LDS dest
    const int acol8 = (lane & 3) ^ ((lane >> 3) & 3);
    int aoff[2];
    #pragma unroll
    for (int j = 0; j < 2; ++j) {
        int r = wv*32 + j*16 + (lane >> 2);
        int arow = ROUTED ? tkl[r] : (m0 + r);
        aoff[j] = arow * KD + acol8 * 8;
    }

    // B staging: same lane mapping as A; wave wv stages B-tile rows (wv%BWG)*16..+15
    const u16* Be = Bb;
    if (KIND == 0) Be += (size_t)e * (size_t)(2*1024*1024);
    if (KIND == 2) Be += (size_t)e * (size_t)(1024*1024);
    const int rB = (wv & (BWG-1))*16 + (lane >> 2);
    int browg;
    if (G1) browg = (rB < 64) ? (nblk*64 + rB) : (NPAIR + nblk*64 + (rB - 64));
    else    browg = nblk*BN + rB;
    const int boff = browg * KD + acol8 * 8;

    auto stageA = [&](int buf, int k0) {
        #pragma unroll
        for (int j = 0; j < 2; ++j) {
            __builtin_amdgcn_global_load_lds(
                (const __attribute__((address_space(1))) uint32_t*)(A + (size_t)(aoff[j] + k0)),
                (__attribute__((address_space(3))) uint32_t*)(&As[buf][(wv*32 + j*16)*32]),
                16, 0, 0);
        }
    };
    auto stageB = [&](int buf, int k0) {
        if (BWG == 8 || wv < BWG) {
            __builtin_amdgcn_global_load_lds(
                (const __attribute__((address_space(1))) uint32_t*)(Be + (size_t)(boff + k0)),
                (__attribute__((address_space(3))) uint32_t*)(&Bs[buf][(wv & (BWG-1))*16*32]),
                16, 0, 0);
        }
    };

    f32x4 acc[2][NF];
    #pragma unroll
    for (int mf = 0; mf < 2; ++mf)
        #pragma unroll
        for (int nf = 0; nf < NF; ++nf)
            acc[mf][nf] = (f32x4){0.f, 0.f, 0.f, 0.f};

    const int slot = lane >> 4;
    const int xoff = ((slot ^ (((lane & 15) >> 1) & 3)) << 4);

    auto mfma_phase = [&](int buf) {
        bf16x8 af[2];
        #pragma unroll
        for (int mf = 0; mf < 2; ++mf) {
            int row = wv*32 + mf*16 + (lane & 15);
            af[mf] = *reinterpret_cast<const bf16x8*>((const char*)&As[buf][0] + row*64 + xoff);
        }
        #pragma unroll
        for (int nf = 0; nf < NF; ++nf) {
            int rowb = nf*16 + (lane & 15);
            bf16x8 bfr = *reinterpret_cast<const bf16x8*>((const char*)&Bs[buf][0] + rowb*64 + xoff);
            #pragma unroll
            for (int mf = 0; mf < 2; ++mf)
                acc[mf][nf] = __builtin_amdgcn_mfma_f32_16x16x32_bf16(af[mf], bfr, acc[mf][nf], 0, 0, 0);
        }
    };

    stageA(0, 0);
    stageB(0, 0);
    __syncthreads();

    for (int kt = 0; kt < KITER; ++kt) {
        const int cur = kt & 1, nxt = cur ^ 1;
        if (kt + 1 < KITER) { stageA(nxt, (kt + 1) * 32); stageB(nxt, (kt + 1) * 32); }
        mfma_phase(cur);
        __syncthreads();
    }

    if constexpr (G1) {
        const int colbase = nblk*64 + (lane & 15);
        #pragma unroll
        for (int mf = 0; mf < 2; ++mf) {
            #pragma unroll
            for (int j = 0; j < 4; ++j) {
                int r = wv*32 + mf*16 + (lane >> 4)*4 + j;
                if (ROUTED && (m0 + r) >= cnt) continue;
                float wgt = (KIND == 0) ? swl[r] : 1.0f;
                size_t orow = (size_t)(ROUTED ? (off + m0 + r) : (m0 + r));
                #pragma unroll
                for (int nf = 0; nf < 4; ++nf) {
                    float g = acc[mf][nf][j];
                    float u = acc[mf][nf+4][j];
                    float hv = (g / (1.f + __expf(-g))) * u * wgt;
                    Hout[orow * NPAIR + colbase + nf*16] = f2b(hv);
                }
            }
        }
    } else {
        const int colbase = nblk*BN + (lane & 15);
        #pragma unroll
        for (int mf = 0; mf < 2; ++mf) {
            #pragma unroll
            for (int j = 0; j < 4; ++j) {
                int r = wv*32 + mf*16 + (lane >> 4)*4 + j;
                if (ROUTED && (m0 + r) >= cnt) continue;
                #pragma unroll
                for (int nf = 0; nf < NF; ++nf) {
                    float v = acc[mf][nf][j];
                    if (KIND == 2) Hout[(size_t)(off + m0 + r) * HID + colbase + nf*16] = f2b(v);
                    else           Out[(size_t)(m0 + r) * HID + colbase + nf*16] = v;
                }
            }
        }
    }
}

// ================= PATH B (fallback, R7-verified): fp32 B with in-loop convert ========
template<int KIND>
__global__ __launch_bounds__(512, 4) void gemm_kernel(
    const u16* __restrict__ A, const float* __restrict__ Bw,
    u16* __restrict__ Hout, float* __restrict__ Out,
    const int* __restrict__ offs, const int* __restrict__ stok,
    const float* __restrict__ sw)
{
    constexpr bool G1     = (KIND == 0 || KIND == 1);
    constexpr bool ROUTED = (KIND == 0 || KIND == 2);
    constexpr int  BM     = 256;
    constexpr int  BN     = (KIND == 3) ? 64 : 128;
    constexpr int  NF     = BN / 16;
    constexpr int  KD     = (KIND == 3) ? 2048 : 1024;
    constexpr int  KITER  = KD / 32;
    constexpr int  NPAIR  = (KIND == 0) ? 1024 : 2048;
    constexpr int  TPR    = 512 / BN;
    constexpr int  CPT    = 32 / TPR;
    constexpr int  BREG   = CPT / 4;

    __shared__ u16 As[2][BM*32];
    __shared__ u16 Bs[2][BN*32];
    __shared__ int   tkl[ROUTED ? BM : 1];
    __shared__ float swl[(KIND == 0) ? BM : 1];

    const int tid  = threadIdx.x;
    const int lane = tid & 63;
    const int wv   = tid >> 6;

    const int e = ROUTED ? blockIdx.z : 0;
    int off = 0, cnt = M_TOK;
    if (ROUTED) { off = offs[e]; cnt = offs[e+1] - off; }
    const int m0 = blockIdx.y * BM;
    if (m0 >= cnt) return;
    const int nblk = blockIdx.x;

    if (ROUTED && tid < BM) {
        int gr = m0 + tid;
        if (KIND == 0) {
            tkl[tid] = (gr < cnt) ? stok[off + gr] : 0;
            swl[tid] = (gr < cnt) ? sw[off + gr] : 0.f;
        } else {
            int r = off + gr; if (r > TOTSLOT-1) r = TOTSLOT-1;
            tkl[tid] = r;
        }
    }
    __syncthreads();

    const int acol8 = (lane & 3) ^ ((lane >> 3) & 3);
    int aoff[2];
    #pragma unroll
    for (int j = 0; j < 2; ++j) {
        int r = wv*32 + j*16 + (lane >> 2);
        int arow = ROUTED ? tkl[r] : (m0 + r);
        aoff[j] = arow * KD + acol8 * 8;
    }

    const float* Be = Bw;
    if (KIND == 0) Be += (size_t)e * (size_t)(2*1024*1024);
    if (KIND == 2) Be += (size_t)e * (size_t)(1024*1024);
    const int rb = tid / TPR;
    const int q  = tid % TPR;
    int brow;
    if (G1) brow = (rb < 64) ? (nblk*64 + rb) : (NPAIR + nblk*64 + (rb - 64));
    else    brow = nblk*BN + rb;
    const float* bsrc = Be + (size_t)brow * KD + q*CPT;

    float4 br[BREG];

    auto stageA = [&](int buf, int k0) {
        #pragma unroll
        for (int j = 0; j < 2; ++j) {
            __builtin_amdgcn_global_load_lds(
                (const __attribute__((address_space(1))) uint32_t*)(A + (size_t)(aoff[j] + k0)),
                (__attribute__((address_space(3))) uint32_t*)(&As[buf][(wv*32 + j*16)*32]),
                16, 0, 0);
        }
    };
    auto loadB = [&](int k0) {
        #pragma unroll
        for (int j = 0; j < BREG; ++j)
            br[j] = *reinterpret_cast<const float4*>(bsrc + k0 + j*4);
    };
    auto storeB = [&](int buf) {
        char* bd = (char*)&Bs[buf][0] + rb*64;
        if constexpr (CPT == 8) {
            u16x8 w;
            w[0] = f2b(br[0].x); w[1] = f2b(br[0].y); w[2] = f2b(br[0].z); w[3] = f2b(br[0].w);
            w[4] = f2b(br[1].x); w[5] = f2b(br[1].y); w[6] = f2b(br[1].z); w[7] = f2b(br[1].w);
            *reinterpret_cast<u16x8*>(bd + ((q ^ ((rb >> 1) & 3)) << 4)) = w;
        } else {
            u16x4 w;
            w[0] = f2b(br[0].x); w[1] = f2b(br[0].y); w[2] = f2b(br[0].z); w[3] = f2b(br[0].w);
            *reinterpret_cast<u16x4*>(bd + (((q>>1) ^ ((rb >> 1) & 3)) << 4) + (q & 1) * 8) = w;
        }
    };

    f32x4 acc[2][NF];
    #pragma unroll
    for (int mf = 0; mf < 2; ++mf)
        #pragma unroll
        for (int nf = 0; nf < NF; ++nf)
            acc[mf][nf] = (f32x4){0.f, 0.f, 0.f, 0.f};

    const int slot = lane >> 4;
    const int xoff = ((slot ^ (((lane & 15) >> 1) & 3)) << 4);

    auto mfma_phase = [&](int buf) {
        bf16x8 af[2];
        #pragma unroll
        for (int mf = 0; mf < 2; ++mf) {
            int row = wv*32 + mf*16 + (lane & 15);
            af[mf] = *reinterpret_cast<const bf16x8*>((const char*)&As[buf][0] + row*64 + xoff);
        }
        #pragma unroll
        for (int nf = 0; nf < NF; ++nf) {
            int rowb = nf*16 + (lane & 15);
            bf16x8 bfr = *reinterpret_cast<const bf16x8*>((const char*)&Bs[buf][0] + rowb*64 + xoff);
            #pragma unroll
            for (int mf = 0; mf < 2; ++mf)
                acc[mf][nf] = __builtin_amdgcn_mfma_f32_16x16x32_bf16(af[mf], bfr, acc[mf][nf], 0, 0, 0);
        }
    };

    stageA(0, 0);
    loadB(0);
    storeB(0);
    __syncthreads();

    for (int kt = 0; kt < KITER; ++kt) {
        const int cur = kt & 1, nxt = cur ^ 1;
        const bool more = (kt + 1 < KITER);
        if (more) { stageA(nxt, (kt + 1) * 32); loadB((kt + 1) * 32); }
        mfma_phase(cur);
        if (more) storeB(nxt);
        __syncthreads();
    }

    if constexpr (G1) {
        const int colbase = nblk*64 + (lane & 15);
        #pragma unroll
        for (int mf = 0; mf < 2; ++mf) {
            #pragma unroll
            for (int j = 0; j < 4; ++j) {
                int r = wv*32 + mf*16 + (lane >> 4)*4 + j;
                if (ROUTED && (m0 + r) >= cnt) continue;
                float wgt = (KIND == 0) ? swl[r] : 1.0f;
                size_t orow = (size_t)(ROUTED ? (off + m0 + r) : (m0 + r));
                #pragma unroll
                for (int nf = 0; nf < 4; ++nf) {
                    float g = acc[mf][nf][j];
                    float u = acc[mf][nf+4][j];
                    float hv = (g / (1.f + __expf(-g))) * u * wgt;
                    Hout[orow * NPAIR + colbase + nf*16] = f2b(hv);
                }
            }
        }
    } else {
        const int colbase = nblk*BN + (lane & 15);
        #pragma unroll
        for (int mf = 0; mf < 2; ++mf) {
            #pragma unroll
            for (int j = 0; j < 4; ++j) {
                int r = wv*32 + mf*16 + (lane >> 4)*4 + j;
                if (ROUTED && (m0 + r) >= cnt) continue;
                #pragma unroll
                for (int nf = 0; nf < NF; ++nf) {
                    float v = acc[mf][nf][j];
                    if (KIND == 2) Hout[(size_t)(off + m0 + r) * HID + colbase + nf*16] = f2b(v);
                    else           Out[(size_t)(m0 + r) * HID + colbase + nf*16] = v;
                }
            }
        }
    }
}

// ---------------- gather-reduce: out[t] += sum_k y[spos[t,k]] ----------------
__global__ __launch_bounds__(256) void reduce_kernel(
    const u16* __restrict__ y, const int* __restrict__ spos, float* __restrict__ out)
{
    int t = blockIdx.x;
    int c = threadIdx.x * 4;
    float4 o = *reinterpret_cast<const float4*>(out + (size_t)t*HID + c);
    #pragma unroll
    for (int k = 0; k < TOPK; ++k) {
        int p = spos[t*TOPK + k];
        u16x4 v = *reinterpret_cast<const u16x4*>(y + (size_t)p*HID + c);
        o.x += b2f(v[0]); o.y += b2f(v[1]); o.z += b2f(v[2]); o.w += b2f(v[3]);
    }
    *reinterpret_cast<float4*>(out + (size_t)t*HID + c) = o;
}

extern "C" void kernel_launch(void* const* d_in, const int* in_sizes, int n_in,
                              void* d_out, int out_size, void* d_ws, size_t ws_size,
                              hipStream_t stream)
{
    const float* x   = (const float*)d_in[0];
    const float* gw  = (const float*)d_in[1];
    const float* w1  = (const float*)d_in[2];
    const float* w2  = (const float*)d_in[3];
    const float* sgu = (const float*)d_in[4];
    const float* sdn = (const float*)d_in[5];
    float* out = (float*)d_out;

    char* p = (char*)d_ws;
    auto carve = [&](size_t bytes) { char* r = p; p += (bytes + 255) & ~(size_t)255; return r; };
    u16*   xb      = (u16*)  carve((size_t)M_TOK * HID * 2);
    u16*   h       = (u16*)  carve((size_t)TOTSLOT * 1024 * 2);
    u16*   hs      = (u16*)  carve((size_t)M_TOK * 2048 * 2);
    u16*   y       = (u16*)  carve((size_t)TOTSLOT * HID * 2);
    float* gwT     = (float*)carve((size_t)HID * NEXP * 4);
    int*   topk_id = (int*)  carve(M_TOK * TOPK * 4);
    float* topk_w  = (float*)carve(M_TOK * TOPK * 4);
    int*   counts  = (int*)  carve(NEXP * 4);
    int*   offs    = (int*)  carve((NEXP + 1) * 4);
    int*   cursor  = (int*)  carve(NEXP * 4);
    int*   stok    = (int*)  carve(TOTSLOT * 4);
    float* sw      = (float*)carve(TOTSLOT * 4);
    int*   spos    = (int*)  carve(TOTSLOT * 4);
    // bf16 weight mirrors (Path A only)
    u16*   w1b     = (u16*)  carve((size_t)NEXP * 2048 * 1024 * 2);  // 256 MB
    u16*   w2b     = (u16*)  carve((size_t)NEXP * 1024 * 1024 * 2);  // 128 MB
    u16*   sgub    = (u16*)  carve((size_t)4096 * 1024 * 2);         // 8 MB
    u16*   sdnb    = (u16*)  carve((size_t)1024 * 2048 * 2);         // 4 MB
    const bool bigws = ((size_t)(p - (char*)d_ws) <= ws_size);

    hipMemsetAsync(counts, 0, NEXP * 4, stream);
    convert_x_kernel<<<(M_TOK*HID/4 + 255)/256, 256, 0, stream>>>(x, xb);
    transpose_gw_kernel<<<(NEXP*HID + 255)/256, 256, 0, stream>>>(gw, gwT);
    router_kernel<<<M_TOK, 64, 0, stream>>>(x, gwT, topk_id, topk_w, counts);
    scan_kernel<<<1, 64, 0, stream>>>(counts, offs, cursor);
    fill_kernel<<<(TOTSLOT + 255)/256, 256, 0, stream>>>(topk_id, topk_w, cursor, stok, sw, spos);

    if (bigws) {
        convert_w_kernel<<<4096, 256, 0, stream>>>(w1,  w1b,  NEXP*2048*1024/4);
        convert_w_kernel<<<4096, 256, 0, stream>>>(w2,  w2b,  NEXP*1024*1024/4);
        convert_w_kernel<<<1024, 256, 0, stream>>>(sgu, sgub, 4096*1024/4);
        convert_w_kernel<<<1024, 256, 0, stream>>>(sdn, sdnb, 1024*2048/4);
        gemm_bf16<1><<<dim3(32,8,1),  512, 0, stream>>>(xb, sgub, hs, nullptr, nullptr, nullptr, nullptr);
        gemm_bf16<3><<<dim3(16,8,1),  512, 0, stream>>>(hs, sdnb, nullptr, out, nullptr, nullptr, nullptr);
        gemm_bf16<0><<<dim3(16,2,64), 512, 0, stream>>>(xb, w1b, h, nullptr, offs, stok, sw);
        gemm_bf16<2><<<dim3(8,2,64),  512, 0, stream>>>(h,  w2b, y, nullptr, offs, stok, sw);
    } else {
        gemm_kernel<1><<<dim3(32,8,1),  512, 0, stream>>>(xb, sgu, hs, nullptr, nullptr, nullptr, nullptr);
        gemm_kernel<3><<<dim3(16,8,1),  512, 0, stream>>>(hs, sdn, nullptr, out, nullptr, nullptr, nullptr);
        gemm_kernel<0><<<dim3(16,2,64), 512, 0, stream>>>(xb, w1, h, nullptr, offs, stok, sw);
        gemm_kernel<2><<<dim3(8,2,64),  512, 0, stream>>>(h, w2, y, nullptr, offs, stok, sw);
    }
    reduce_kernel<<<M_TOK, 256, 0, stream>>>(y, spos, out);
}

// Round 12
// 605.189 us; speedup vs baseline: 1.1570x; 1.1548x over previous
//
#include <hip/hip_runtime.h>
#include <stdint.h>

#define M_TOK 2048
#define HID   1024
#define NEXP  64
#define TOPK  6
#define TOTSLOT (M_TOK*TOPK)   // 12288

typedef unsigned short u16;
typedef __attribute__((ext_vector_type(4))) u16   u16x4;
typedef __attribute__((ext_vector_type(8))) u16   u16x8;
typedef __attribute__((ext_vector_type(4))) float f32x4;
typedef __attribute__((ext_vector_type(8))) short bf16x8;

__device__ __forceinline__ u16 f2b(float f) {
    union { float f; uint32_t u; } v; v.f = f;
    uint32_t r = v.u + 0x7FFFu + ((v.u >> 16) & 1u);
    return (u16)(r >> 16);
}
__device__ __forceinline__ float b2f(u16 b) {
    union { uint32_t u; float f; } v; v.u = ((uint32_t)b) << 16; return v.f;
}

// ---------------- x fp32 -> bf16 ----------------
__global__ __launch_bounds__(256) void convert_x_kernel(const float* __restrict__ x,
                                                        u16* __restrict__ xb) {
    int i = (blockIdx.x * 256 + threadIdx.x) * 4;
    float4 v = *reinterpret_cast<const float4*>(x + i);
    u16x4 o; o[0] = f2b(v.x); o[1] = f2b(v.y); o[2] = f2b(v.z); o[3] = f2b(v.w);
    *reinterpret_cast<u16x4*>(xb + i) = o;
}

// ---------------- gw transpose: gwT[k][e] so router lanes read coalesced ----------------
__global__ __launch_bounds__(256) void transpose_gw_kernel(const float* __restrict__ gw,
                                                           float* __restrict__ gwT) {
    int i = blockIdx.x * 256 + threadIdx.x;   // 65536 elements
    int e = i >> 10, k = i & 1023;
    gwT[k * NEXP + e] = gw[i];
}

// ---------------- router: fp64 logits (coalesced gwT), grouped topk ----------------
__global__ __launch_bounds__(64) void router_kernel(
    const float* __restrict__ x, const float* __restrict__ gwT,
    int* __restrict__ topk_id, float* __restrict__ topk_w, int* __restrict__ counts)
{
    int t = blockIdx.x, lane = threadIdx.x;
    __shared__ float xr[HID];
    for (int k = lane; k < HID; k += 64) xr[k] = x[(size_t)t * HID + k];
    __syncthreads();
    double s0 = 0.0, s1 = 0.0, s2 = 0.0, s3 = 0.0;
    for (int k = 0; k < HID; k += 4) {
        s0 += (double)xr[k]   * (double)gwT[(k)   * NEXP + lane];
        s1 += (double)xr[k+1] * (double)gwT[(k+1) * NEXP + lane];
        s2 += (double)xr[k+2] * (double)gwT[(k+2) * NEXP + lane];
        s3 += (double)xr[k+3] * (double)gwT[(k+3) * NEXP + lane];
    }
    double s = (s0 + s1) + (s2 + s3);
    __shared__ double lg[NEXP];
    __shared__ float  pr[NEXP];
    float sf = (float)s;
    float mx = sf;
    for (int o = 32; o; o >>= 1) mx = fmaxf(mx, __shfl_xor(mx, o));
    float ev = __expf(sf - mx);
    float sum = ev;
    for (int o = 32; o; o >>= 1) sum += __shfl_xor(sum, o);
    lg[lane] = s; pr[lane] = ev / sum;
    __syncthreads();
    if (lane == 0) {
        double gs[8];
        #pragma unroll
        for (int g = 0; g < 8; ++g) {
            double m = lg[g*8];
            #pragma unroll
            for (int i = 1; i < 8; ++i) m = fmax(m, lg[g*8+i]);
            gs[g] = m;
        }
        unsigned gsel = 0;
        for (int r = 0; r < 3; ++r) {
            int bi = 0; double bv = -1e300;
            for (int g = 0; g < 8; ++g)
                if (!((gsel>>g)&1u) && gs[g] > bv) { bv = gs[g]; bi = g; }
            gsel |= 1u << bi;
        }
        unsigned long long taken = 0;
        for (int r = 0; r < TOPK; ++r) {
            int bi = 0; double bv = -1e300;
            for (int e = 0; e < NEXP; ++e) {
                if (!((gsel >> (e>>3)) & 1u)) continue;
                if ((taken >> e) & 1ull) continue;
                if (lg[e] > bv) { bv = lg[e]; bi = e; }
            }
            taken |= 1ull << bi;
            topk_id[t*TOPK + r] = bi;
            topk_w[t*TOPK + r] = pr[bi];
            atomicAdd(&counts[bi], 1);
        }
    }
}

__global__ void scan_kernel(const int* __restrict__ counts, int* __restrict__ offs,
                            int* __restrict__ cursor) {
    if (threadIdx.x == 0) {
        int acc = 0;
        for (int e = 0; e < NEXP; ++e) { offs[e] = acc; cursor[e] = acc; acc += counts[e]; }
        offs[NEXP] = acc;
    }
}

__global__ __launch_bounds__(256) void fill_kernel(
    const int* __restrict__ topk_id, const float* __restrict__ topk_w,
    int* __restrict__ cursor, int* __restrict__ stok, float* __restrict__ sw,
    int* __restrict__ spos)
{
    int idx = blockIdx.x*256 + threadIdx.x;
    if (idx >= TOTSLOT) return;
    int e = topk_id[idx];
    int pos = atomicAdd(&cursor[e], 1);
    stok[pos] = idx / TOPK;
    sw[pos] = topk_w[idx];
    spos[idx] = pos;
}

// ---------------- unified MFMA GEMM: BK=32, 512 thr, XCD-aware block swizzle -------
// KIND 0: routed gate/up  BM=256 BN=128  A=xb[tok] K=1024, B=w1[e] -> h (silu*up*w)
// KIND 1: shared gate/up  BM=256 BN=128  A=xb      K=1024, B=sgu  -> hs (bf16)
// KIND 2: routed down     BM=256 BN=128  A=h       K=1024, B=w2[e]-> y  (bf16)
// KIND 3: shared down     BM=128 BN=64   A=hs      K=2048, B=sdn  -> Out (f32)
// Swizzle (T1): assuming XCD = linear_block_id % 8, co-locate each expert's blocks
// (and every B-sharing y-group) on one XCD so w-row reuse + token-gather hit that L2.
template<int KIND>
__global__ __launch_bounds__(512, 4) void gemm_kernel(
    const u16* __restrict__ A, const float* __restrict__ Bw,
    u16* __restrict__ Hout, float* __restrict__ Out,
    const int* __restrict__ offs, const int* __restrict__ stok,
    const float* __restrict__ sw)
{
    constexpr bool G1     = (KIND == 0 || KIND == 1);
    constexpr bool ROUTED = (KIND == 0 || KIND == 2);
    constexpr int  BM     = (KIND == 3) ? 128 : 256;
    constexpr int  MR     = BM / 128;     // M fragments per wave (2 or 1)
    constexpr int  BN     = (KIND == 3) ? 64 : 128;
    constexpr int  NF     = BN / 16;
    constexpr int  KD     = (KIND == 3) ? 2048 : 1024;
    constexpr int  KITER  = KD / 32;
    constexpr int  NPAIR  = (KIND == 0) ? 1024 : 2048;
    constexpr int  TPR    = 512 / BN;     // B-stage threads per row (4 or 8)
    constexpr int  CPT    = 32 / TPR;     // B fp32 cols per thread (8 or 4)
    constexpr int  BREG   = CPT / 4;      // float4 per thread (2 or 1)

    __shared__ u16 As[2][BM*32];
    __shared__ u16 Bs[2][BN*32];
    __shared__ int   tkl[ROUTED ? BM : 1];
    __shared__ float swl[(KIND == 0) ? BM : 1];

    const int tid  = threadIdx.x;
    const int lane = tid & 63;
    const int wv   = tid >> 6;

    // ---- XCD-aware swizzle: rid -> (e, my, nblk) ----
    const int rid = blockIdx.x + gridDim.x * (blockIdx.y + gridDim.y * blockIdx.z);
    int nblk, my, e = 0;
    if constexpr (KIND == 0) {            // 2048 blocks: 8 experts/XCD, 32 blocks/expert
        int slot = rid >> 3;
        e = (rid & 7) * 8 + (slot >> 5);
        int sub = slot & 31; my = sub & 1; nblk = sub >> 1;
    } else if constexpr (KIND == 2) {     // 1024 blocks: 8 experts/XCD, 16 blocks/expert
        int slot = rid >> 3;
        e = (rid & 7) * 8 + (slot >> 4);
        int sub = slot & 15; my = sub & 1; nblk = sub >> 1;
    } else if constexpr (KIND == 1) {     // 256 blocks: 4 nblk/XCD, 8 y-blocks together
        int slot = rid >> 3;
        nblk = (rid & 7) * 4 + (slot >> 3); my = slot & 7;
    } else {                              // 256 blocks: 2 nblk/XCD, 16 y-blocks together
        int slot = rid >> 3;
        nblk = (rid & 7) * 2 + (slot >> 4); my = slot & 15;
    }

    int off = 0, cnt = M_TOK;
    if (ROUTED) { off = offs[e]; cnt = offs[e+1] - off; }
    const int m0 = my * BM;
    if (m0 >= cnt) return;

    if (ROUTED && tid < BM) {
        int gr = m0 + tid;
        if (KIND == 0) {
            tkl[tid] = (gr < cnt) ? stok[off + gr] : 0;
            swl[tid] = (gr < cnt) ? sw[off + gr] : 0.f;
        } else {
            int r = off + gr; if (r > TOTSLOT-1) r = TOTSLOT-1;
            tkl[tid] = r;
        }
    }
    __syncthreads();

    // A staging (R7-verified): pre-swizzled source chunk, linear LDS dest
    const int acol8 = (lane & 3) ^ ((lane >> 3) & 3);
    int aoff[MR];
    #pragma unroll
    for (int j = 0; j < MR; ++j) {
        int r = wv*(16*MR) + j*16 + (lane >> 2);
        int arow = ROUTED ? tkl[r] : (m0 + r);
        aoff[j] = arow * KD + acol8 * 8;
    }

    const float* Be = Bw;
    if (KIND == 0) Be += (size_t)e * (size_t)(2*1024*1024);
    if (KIND == 2) Be += (size_t)e * (size_t)(1024*1024);
    const int rb = tid / TPR;
    const int q  = tid % TPR;
    int brow;
    if (G1) brow = (rb < 64) ? (nblk*64 + rb) : (NPAIR + nblk*64 + (rb - 64));
    else    brow = nblk*BN + rb;
    const float* bsrc = Be + (size_t)brow * KD + q*CPT;

    float4 br[BREG];

    auto stageA = [&](int buf, int k0) {
        #pragma unroll
        for (int j = 0; j < MR; ++j) {
            __builtin_amdgcn_global_load_lds(
                (const __attribute__((address_space(1))) uint32_t*)(A + (size_t)(aoff[j] + k0)),
                (__attribute__((address_space(3))) uint32_t*)(&As[buf][(wv*(16*MR) + j*16)*32]),
                16, 0, 0);
        }
    };
    auto loadB = [&](int k0) {
        #pragma unroll
        for (int j = 0; j < BREG; ++j)
            br[j] = *reinterpret_cast<const float4*>(bsrc + k0 + j*4);
    };
    auto storeB = [&](int buf) {
        char* bd = (char*)&Bs[buf][0] + rb*64;
        if constexpr (CPT == 8) {
            u16x8 w;
            w[0] = f2b(br[0].x); w[1] = f2b(br[0].y); w[2] = f2b(br[0].z); w[3] = f2b(br[0].w);
            w[4] = f2b(br[1].x); w[5] = f2b(br[1].y); w[6] = f2b(br[1].z); w[7] = f2b(br[1].w);
            *reinterpret_cast<u16x8*>(bd + ((q ^ ((rb >> 1) & 3)) << 4)) = w;
        } else {
            u16x4 w;
            w[0] = f2b(br[0].x); w[1] = f2b(br[0].y); w[2] = f2b(br[0].z); w[3] = f2b(br[0].w);
            *reinterpret_cast<u16x4*>(bd + (((q>>1) ^ ((rb >> 1) & 3)) << 4) + (q & 1) * 8) = w;
        }
    };

    f32x4 acc[MR][NF];
    #pragma unroll
    for (int mf = 0; mf < MR; ++mf)
        #pragma unroll
        for (int nf = 0; nf < NF; ++nf)
            acc[mf][nf] = (f32x4){0.f, 0.f, 0.f, 0.f};

    const int slot = lane >> 4;
    const int xoff = ((slot ^ (((lane & 15) >> 1) & 3)) << 4);

    auto mfma_phase = [&](int buf) {
        bf16x8 af[MR];
        #pragma unroll
        for (int mf = 0; mf < MR; ++mf) {
            int row = wv*(16*MR) + mf*16 + (lane & 15);
            af[mf] = *reinterpret_cast<const bf16x8*>((const char*)&As[buf][0] + row*64 + xoff);
        }
        #pragma unroll
        for (int nf = 0; nf < NF; ++nf) {
            int rowb = nf*16 + (lane & 15);
            bf16x8 bfr = *reinterpret_cast<const bf16x8*>((const char*)&Bs[buf][0] + rowb*64 + xoff);
            #pragma unroll
            for (int mf = 0; mf < MR; ++mf)
                acc[mf][nf] = __builtin_amdgcn_mfma_f32_16x16x32_bf16(af[mf], bfr, acc[mf][nf], 0, 0, 0);
        }
    };

    stageA(0, 0);
    loadB(0);
    storeB(0);
    __syncthreads();

    for (int kt = 0; kt < KITER; ++kt) {
        const int cur = kt & 1, nxt = cur ^ 1;
        const bool more = (kt + 1 < KITER);
        if (more) { stageA(nxt, (kt + 1) * 32); loadB((kt + 1) * 32); }
        mfma_phase(cur);
        if (more) storeB(nxt);
        __syncthreads();
    }

    if constexpr (G1) {
        const int colbase = nblk*64 + (lane & 15);
        #pragma unroll
        for (int mf = 0; mf < MR; ++mf) {
            #pragma unroll
            for (int j = 0; j < 4; ++j) {
                int r = wv*(16*MR) + mf*16 + (lane >> 4)*4 + j;
                if (ROUTED && (m0 + r) >= cnt) continue;
                float wgt = (KIND == 0) ? swl[r] : 1.0f;
                size_t orow = (size_t)(ROUTED ? (off + m0 + r) : (m0 + r));
                #pragma unroll
                for (int nf = 0; nf < 4; ++nf) {
                    float g = acc[mf][nf][j];
                    float u = acc[mf][nf+4][j];
                    float hv = (g / (1.f + __expf(-g))) * u * wgt;
                    Hout[orow * NPAIR + colbase + nf*16] = f2b(hv);
                }
            }
        }
    } else {
        const int colbase = nblk*BN + (lane & 15);
        #pragma unroll
        for (int mf = 0; mf < MR; ++mf) {
            #pragma unroll
            for (int j = 0; j < 4; ++j) {
                int r = wv*(16*MR) + mf*16 + (lane >> 4)*4 + j;
                if (ROUTED && (m0 + r) >= cnt) continue;
                #pragma unroll
                for (int nf = 0; nf < NF; ++nf) {
                    float v = acc[mf][nf][j];
                    if (KIND == 2) Hout[(size_t)(off + m0 + r) * HID + colbase + nf*16] = f2b(v);
                    else           Out[(size_t)(m0 + r) * HID + colbase + nf*16] = v;
                }
            }
        }
    }
}

// ---------------- gather-reduce: out[t] += sum_k y[spos[t,k]] ----------------
__global__ __launch_bounds__(256) void reduce_kernel(
    const u16* __restrict__ y, const int* __restrict__ spos, float* __restrict__ out)
{
    int t = blockIdx.x;
    int c = threadIdx.x * 4;
    float4 o = *reinterpret_cast<const float4*>(out + (size_t)t*HID + c);
    #pragma unroll
    for (int k = 0; k < TOPK; ++k) {
        int p = spos[t*TOPK + k];
        u16x4 v = *reinterpret_cast<const u16x4*>(y + (size_t)p*HID + c);
        o.x += b2f(v[0]); o.y += b2f(v[1]); o.z += b2f(v[2]); o.w += b2f(v[3]);
    }
    *reinterpret_cast<float4*>(out + (size_t)t*HID + c) = o;
}

extern "C" void kernel_launch(void* const* d_in, const int* in_sizes, int n_in,
                              void* d_out, int out_size, void* d_ws, size_t ws_size,
                              hipStream_t stream)
{
    const float* x   = (const float*)d_in[0];
    const float* gw  = (const float*)d_in[1];
    const float* w1  = (const float*)d_in[2];
    const float* w2  = (const float*)d_in[3];
    const float* sgu = (const float*)d_in[4];
    const float* sdn = (const float*)d_in[5];
    float* out = (float*)d_out;

    char* p = (char*)d_ws;
    auto carve = [&](size_t bytes) { char* r = p; p += (bytes + 255) & ~(size_t)255; return r; };
    u16*   xb      = (u16*)  carve((size_t)M_TOK * HID * 2);
    u16*   h       = (u16*)  carve((size_t)TOTSLOT * 1024 * 2);
    u16*   hs      = (u16*)  carve((size_t)M_TOK * 2048 * 2);
    u16*   y       = (u16*)  carve((size_t)TOTSLOT * HID * 2);
    float* gwT     = (float*)carve((size_t)HID * NEXP * 4);
    int*   topk_id = (int*)  carve(M_TOK * TOPK * 4);
    float* topk_w  = (float*)carve(M_TOK * TOPK * 4);
    int*   counts  = (int*)  carve(NEXP * 4);
    int*   offs    = (int*)  carve((NEXP + 1) * 4);
    int*   cursor  = (int*)  carve(NEXP * 4);
    int*   stok    = (int*)  carve(TOTSLOT * 4);
    float* sw      = (float*)carve(TOTSLOT * 4);
    int*   spos    = (int*)  carve(TOTSLOT * 4);

    hipMemsetAsync(counts, 0, NEXP * 4, stream);
    convert_x_kernel<<<(M_TOK*HID/4 + 255)/256, 256, 0, stream>>>(x, xb);
    transpose_gw_kernel<<<(NEXP*HID + 255)/256, 256, 0, stream>>>(gw, gwT);
    router_kernel<<<M_TOK, 64, 0, stream>>>(x, gwT, topk_id, topk_w, counts);
    scan_kernel<<<1, 64, 0, stream>>>(counts, offs, cursor);
    fill_kernel<<<(TOTSLOT + 255)/256, 256, 0, stream>>>(topk_id, topk_w, cursor, stok, sw, spos);

    // shared gate/up, routed gate/up, routed down, shared down (full grid), gather
    gemm_kernel<1><<<dim3(32,8,1),  512, 0, stream>>>(xb, sgu, hs, nullptr, nullptr, nullptr, nullptr);
    gemm_kernel<0><<<dim3(16,2,64), 512, 0, stream>>>(xb, w1, h, nullptr, offs, stok, sw);
    gemm_kernel<2><<<dim3(8,2,64),  512, 0, stream>>>(h, w2, y, nullptr, offs, stok, sw);
    gemm_kernel<3><<<dim3(16,16,1), 512, 0, stream>>>(hs, sdn, nullptr, out, nullptr, nullptr, nullptr);
    reduce_kernel<<<M_TOK, 256, 0, stream>>>(y, spos, out);
}

// Round 13
// 576.404 us; speedup vs baseline: 1.2148x; 1.0499x over previous
//
#include <hip/hip_runtime.h>
#include <stdint.h>

#define M_TOK 2048
#define HID   1024
#define NEXP  64
#define TOPK  6
#define TOTSLOT (M_TOK*TOPK)   // 12288

typedef unsigned short u16;
typedef __attribute__((ext_vector_type(4))) u16   u16x4;
typedef __attribute__((ext_vector_type(8))) u16   u16x8;
typedef __attribute__((ext_vector_type(4))) float f32x4;
typedef __attribute__((ext_vector_type(8))) short bf16x8;

__device__ __forceinline__ u16 f2b(float f) {
    union { float f; uint32_t u; } v; v.f = f;
    uint32_t r = v.u + 0x7FFFu + ((v.u >> 16) & 1u);
    return (u16)(r >> 16);
}
__device__ __forceinline__ float b2f(u16 b) {
    union { uint32_t u; float f; } v; v.u = ((uint32_t)b) << 16; return v.f;
}

// ---------------- prep: x fp32->bf16 (blocks 0..2047) + gw transpose (2048..2303) ----
__global__ __launch_bounds__(256) void prep_kernel(const float* __restrict__ x,
                                                   u16* __restrict__ xb,
                                                   const float* __restrict__ gw,
                                                   float* __restrict__ gwT) {
    int b = blockIdx.x;
    if (b < 2048) {
        int i = (b * 256 + threadIdx.x) * 4;
        float4 v = *reinterpret_cast<const float4*>(x + i);
        u16x4 o; o[0] = f2b(v.x); o[1] = f2b(v.y); o[2] = f2b(v.z); o[3] = f2b(v.w);
        *reinterpret_cast<u16x4*>(xb + i) = o;
    } else {
        int i = (b - 2048) * 256 + threadIdx.x;   // 65536 elements
        int e = i >> 10, k = i & 1023;
        gwT[k * NEXP + e] = gw[i];
    }
}

// ---------------- router: fp64 logits (coalesced gwT), grouped topk ----------------
__global__ __launch_bounds__(64) void router_kernel(
    const float* __restrict__ x, const float* __restrict__ gwT,
    int* __restrict__ topk_id, float* __restrict__ topk_w, int* __restrict__ counts)
{
    int t = blockIdx.x, lane = threadIdx.x;
    __shared__ float xr[HID];
    for (int k = lane; k < HID; k += 64) xr[k] = x[(size_t)t * HID + k];
    __syncthreads();
    double s0 = 0.0, s1 = 0.0, s2 = 0.0, s3 = 0.0;
    for (int k = 0; k < HID; k += 4) {
        s0 += (double)xr[k]   * (double)gwT[(k)   * NEXP + lane];
        s1 += (double)xr[k+1] * (double)gwT[(k+1) * NEXP + lane];
        s2 += (double)xr[k+2] * (double)gwT[(k+2) * NEXP + lane];
        s3 += (double)xr[k+3] * (double)gwT[(k+3) * NEXP + lane];
    }
    double s = (s0 + s1) + (s2 + s3);
    __shared__ double lg[NEXP];
    __shared__ float  pr[NEXP];
    float sf = (float)s;
    float mx = sf;
    for (int o = 32; o; o >>= 1) mx = fmaxf(mx, __shfl_xor(mx, o));
    float ev = __expf(sf - mx);
    float sum = ev;
    for (int o = 32; o; o >>= 1) sum += __shfl_xor(sum, o);
    lg[lane] = s; pr[lane] = ev / sum;
    __syncthreads();
    if (lane == 0) {
        double gs[8];
        #pragma unroll
        for (int g = 0; g < 8; ++g) {
            double m = lg[g*8];
            #pragma unroll
            for (int i = 1; i < 8; ++i) m = fmax(m, lg[g*8+i]);
            gs[g] = m;
        }
        unsigned gsel = 0;
        for (int r = 0; r < 3; ++r) {
            int bi = 0; double bv = -1e300;
            for (int g = 0; g < 8; ++g)
                if (!((gsel>>g)&1u) && gs[g] > bv) { bv = gs[g]; bi = g; }
            gsel |= 1u << bi;
        }
        unsigned long long taken = 0;
        for (int r = 0; r < TOPK; ++r) {
            int bi = 0; double bv = -1e300;
            for (int e = 0; e < NEXP; ++e) {
                if (!((gsel >> (e>>3)) & 1u)) continue;
                if ((taken >> e) & 1ull) continue;
                if (lg[e] > bv) { bv = lg[e]; bi = e; }
            }
            taken |= 1ull << bi;
            topk_id[t*TOPK + r] = bi;
            topk_w[t*TOPK + r] = pr[bi];
            atomicAdd(&counts[bi], 1);
        }
    }
}

__global__ void scan_kernel(const int* __restrict__ counts, int* __restrict__ offs,
                            int* __restrict__ cursor) {
    if (threadIdx.x == 0) {
        int acc = 0;
        for (int e = 0; e < NEXP; ++e) { offs[e] = acc; cursor[e] = acc; acc += counts[e]; }
        offs[NEXP] = acc;
    }
}

__global__ __launch_bounds__(256) void fill_kernel(
    const int* __restrict__ topk_id, const float* __restrict__ topk_w,
    int* __restrict__ cursor, int* __restrict__ stok, float* __restrict__ sw,
    int* __restrict__ spos)
{
    int idx = blockIdx.x*256 + threadIdx.x;
    if (idx >= TOTSLOT) return;
    int e = topk_id[idx];
    int pos = atomicAdd(&cursor[e], 1);
    stok[pos] = idx / TOPK;
    sw[pos] = topk_w[idx];
    spos[idx] = pos;
}

// ---------------- R12-proven GEMM body as a device function ----------------
// KIND 0: routed gate/up  BM=256 BN=128  A=xb[tok] K=1024, B=w1[e] -> h (silu*up*w)
// KIND 1: shared gate/up  BM=256 BN=128  A=xb      K=1024, B=sgu  -> hs (bf16)
// KIND 2: routed down     BM=256 BN=128  A=h       K=1024, B=w2[e]-> y  (bf16)
// KIND 3: shared down     BM=128 BN=64   A=hs      K=2048, B=sdn  -> Out (f32)
template<int KIND>
__device__ __forceinline__ void gemm_core(
    const int e, const int my, const int nblk,
    const u16* __restrict__ A, const float* __restrict__ Bw,
    u16* __restrict__ Hout, float* __restrict__ Out,
    const int* __restrict__ offs, const int* __restrict__ stok,
    const float* __restrict__ sw,
    u16* __restrict__ AsR, u16* __restrict__ BsR,
    int* __restrict__ tkl, float* __restrict__ swl)
{
    constexpr bool G1     = (KIND == 0 || KIND == 1);
    constexpr bool ROUTED = (KIND == 0 || KIND == 2);
    constexpr int  BM     = (KIND == 3) ? 128 : 256;
    constexpr int  MR     = BM / 128;
    constexpr int  BN     = (KIND == 3) ? 64 : 128;
    constexpr int  NF     = BN / 16;
    constexpr int  KD     = (KIND == 3) ? 2048 : 1024;
    constexpr int  KITER  = KD / 32;
    constexpr int  NPAIR  = (KIND == 0) ? 1024 : 2048;
    constexpr int  TPR    = 512 / BN;
    constexpr int  CPT    = 32 / TPR;
    constexpr int  BREG   = CPT / 4;

    const int tid  = threadIdx.x;
    const int lane = tid & 63;
    const int wv   = tid >> 6;

    int off = 0, cnt = M_TOK;
    if (ROUTED) { off = offs[e]; cnt = offs[e+1] - off; }
    const int m0 = my * BM;
    if (m0 >= cnt) return;

    if (ROUTED && tid < BM) {
        int gr = m0 + tid;
        if (KIND == 0) {
            tkl[tid] = (gr < cnt) ? stok[off + gr] : 0;
            swl[tid] = (gr < cnt) ? sw[off + gr] : 0.f;
        } else {
            int r = off + gr; if (r > TOTSLOT-1) r = TOTSLOT-1;
            tkl[tid] = r;
        }
    }
    __syncthreads();

    const int acol8 = (lane & 3) ^ ((lane >> 3) & 3);
    int aoff[MR];
    #pragma unroll
    for (int j = 0; j < MR; ++j) {
        int r = wv*(16*MR) + j*16 + (lane >> 2);
        int arow = ROUTED ? tkl[r] : (m0 + r);
        aoff[j] = arow * KD + acol8 * 8;
    }

    const float* Be = Bw;
    if (KIND == 0) Be += (size_t)e * (size_t)(2*1024*1024);
    if (KIND == 2) Be += (size_t)e * (size_t)(1024*1024);
    const int rb = tid / TPR;
    const int q  = tid % TPR;
    int brow;
    if (G1) brow = (rb < 64) ? (nblk*64 + rb) : (NPAIR + nblk*64 + (rb - 64));
    else    brow = nblk*BN + rb;
    const float* bsrc = Be + (size_t)brow * KD + q*CPT;

    float4 br[BREG];

    auto stageA = [&](int buf, int k0) {
        #pragma unroll
        for (int j = 0; j < MR; ++j) {
            __builtin_amdgcn_global_load_lds(
                (const __attribute__((address_space(1))) uint32_t*)(A + (size_t)(aoff[j] + k0)),
                (__attribute__((address_space(3))) uint32_t*)(AsR + buf*(BM*32) + (wv*(16*MR) + j*16)*32),
                16, 0, 0);
        }
    };
    auto loadB = [&](int k0) {
        #pragma unroll
        for (int j = 0; j < BREG; ++j)
            br[j] = *reinterpret_cast<const float4*>(bsrc + k0 + j*4);
    };
    auto storeB = [&](int buf) {
        char* bd = (char*)(BsR + buf*(BN*32)) + rb*64;
        if constexpr (CPT == 8) {
            u16x8 w;
            w[0] = f2b(br[0].x); w[1] = f2b(br[0].y); w[2] = f2b(br[0].z); w[3] = f2b(br[0].w);
            w[4] = f2b(br[1].x); w[5] = f2b(br[1].y); w[6] = f2b(br[1].z); w[7] = f2b(br[1].w);
            *reinterpret_cast<u16x8*>(bd + ((q ^ ((rb >> 1) & 3)) << 4)) = w;
        } else {
            u16x4 w;
            w[0] = f2b(br[0].x); w[1] = f2b(br[0].y); w[2] = f2b(br[0].z); w[3] = f2b(br[0].w);
            *reinterpret_cast<u16x4*>(bd + (((q>>1) ^ ((rb >> 1) & 3)) << 4) + (q & 1) * 8) = w;
        }
    };

    f32x4 acc[MR][NF];
    #pragma unroll
    for (int mf = 0; mf < MR; ++mf)
        #pragma unroll
        for (int nf = 0; nf < NF; ++nf)
            acc[mf][nf] = (f32x4){0.f, 0.f, 0.f, 0.f};

    const int slot = lane >> 4;
    const int xoff = ((slot ^ (((lane & 15) >> 1) & 3)) << 4);

    auto mfma_phase = [&](int buf) {
        bf16x8 af[MR];
        #pragma unroll
        for (int mf = 0; mf < MR; ++mf) {
            int row = wv*(16*MR) + mf*16 + (lane & 15);
            af[mf] = *reinterpret_cast<const bf16x8*>((const char*)(AsR + buf*(BM*32)) + row*64 + xoff);
        }
        #pragma unroll
        for (int nf = 0; nf < NF; ++nf) {
            int rowb = nf*16 + (lane & 15);
            bf16x8 bfr = *reinterpret_cast<const bf16x8*>((const char*)(BsR + buf*(BN*32)) + rowb*64 + xoff);
            #pragma unroll
            for (int mf = 0; mf < MR; ++mf)
                acc[mf][nf] = __builtin_amdgcn_mfma_f32_16x16x32_bf16(af[mf], bfr, acc[mf][nf], 0, 0, 0);
        }
    };

    stageA(0, 0);
    loadB(0);
    storeB(0);
    __syncthreads();

    for (int kt = 0; kt < KITER; ++kt) {
        const int cur = kt & 1, nxt = cur ^ 1;
        const bool more = (kt + 1 < KITER);
        if (more) { stageA(nxt, (kt + 1) * 32); loadB((kt + 1) * 32); }
        mfma_phase(cur);
        if (more) storeB(nxt);
        __syncthreads();
    }

    if constexpr (G1) {
        const int colbase = nblk*64 + (lane & 15);
        #pragma unroll
        for (int mf = 0; mf < MR; ++mf) {
            #pragma unroll
            for (int j = 0; j < 4; ++j) {
                int r = wv*(16*MR) + mf*16 + (lane >> 4)*4 + j;
                if (ROUTED && (m0 + r) >= cnt) continue;
                float wgt = (KIND == 0) ? swl[r] : 1.0f;
                size_t orow = (size_t)(ROUTED ? (off + m0 + r) : (m0 + r));
                #pragma unroll
                for (int nf = 0; nf < 4; ++nf) {
                    float g = acc[mf][nf][j];
                    float u = acc[mf][nf+4][j];
                    float hv = (g / (1.f + __expf(-g))) * u * wgt;
                    Hout[orow * NPAIR + colbase + nf*16] = f2b(hv);
                }
            }
        }
    } else {
        const int colbase = nblk*BN + (lane & 15);
        #pragma unroll
        for (int mf = 0; mf < MR; ++mf) {
            #pragma unroll
            for (int j = 0; j < 4; ++j) {
                int r = wv*(16*MR) + mf*16 + (lane >> 4)*4 + j;
                if (ROUTED && (m0 + r) >= cnt) continue;
                #pragma unroll
                for (int nf = 0; nf < NF; ++nf) {
                    float v = acc[mf][nf][j];
                    if (KIND == 2) Hout[(size_t)(off + m0 + r) * HID + colbase + nf*16] = f2b(v);
                    else           Out[(size_t)(m0 + r) * HID + colbase + nf*16] = v;
                }
            }
        }
    }
}

// ---------------- fused launch 1: routed gate/up (0..2047) + shared gate/up (2048..2303)
__global__ __launch_bounds__(512, 4) void gemm01_kernel(
    const u16* __restrict__ xb, const float* __restrict__ w1, const float* __restrict__ sgu,
    u16* __restrict__ h, u16* __restrict__ hs,
    const int* __restrict__ offs, const int* __restrict__ stok, const float* __restrict__ sw)
{
    __shared__ u16 AsR[2*256*32];
    __shared__ u16 BsR[2*128*32];
    __shared__ int   tkl[256];
    __shared__ float swl[256];
    const int rid = blockIdx.x;
    if (rid < 2048) {           // 8 experts/XCD, 32 blocks/expert
        int slot = rid >> 3;
        int e = (rid & 7) * 8 + (slot >> 5);
        int sub = slot & 31;
        gemm_core<0>(e, sub & 1, sub >> 1, xb, w1, h, nullptr, offs, stok, sw, AsR, BsR, tkl, swl);
    } else {                    // shared gate/up: 4 nblk/XCD, 8 y-blocks together
        int sid = rid - 2048;
        int slot = sid >> 3;
        gemm_core<1>(0, slot & 7, (sid & 7) * 4 + (slot >> 3), xb, sgu, hs, nullptr,
                     offs, stok, sw, AsR, BsR, tkl, swl);
    }
}

// ---------------- fused launch 2: shared down (0..255, longest-first) + routed down ----
__global__ __launch_bounds__(512, 4) void gemm23_kernel(
    const u16* __restrict__ h, const u16* __restrict__ hs,
    const float* __restrict__ w2, const float* __restrict__ sdn,
    u16* __restrict__ y, float* __restrict__ out,
    const int* __restrict__ offs, const int* __restrict__ stok, const float* __restrict__ sw)
{
    __shared__ u16 AsR[2*256*32];
    __shared__ u16 BsR[2*128*32];
    __shared__ int   tkl[256];
    __shared__ float swl[256];
    const int rid = blockIdx.x;
    if (rid >= 256) {           // routed down: 8 experts/XCD, 16 blocks/expert
        int r2 = rid - 256;
        int slot = r2 >> 3;
        int e = (r2 & 7) * 8 + (slot >> 4);
        int sub = slot & 15;
        gemm_core<2>(e, sub & 1, sub >> 1, h, w2, y, nullptr, offs, stok, sw, AsR, BsR, tkl, swl);
    } else {                    // shared down (K=2048 long blocks scheduled first)
        int slot = rid >> 3;
        gemm_core<3>(0, slot & 15, (rid & 7) * 2 + (slot >> 4), hs, sdn, nullptr, out,
                     offs, stok, sw, AsR, BsR, tkl, swl);
    }
}

// ---------------- gather-reduce: out[t] += sum_k y[spos[t,k]] ----------------
__global__ __launch_bounds__(256) void reduce_kernel(
    const u16* __restrict__ y, const int* __restrict__ spos, float* __restrict__ out)
{
    int t = blockIdx.x;
    int c = threadIdx.x * 4;
    float4 o = *reinterpret_cast<const float4*>(out + (size_t)t*HID + c);
    #pragma unroll
    for (int k = 0; k < TOPK; ++k) {
        int p = spos[t*TOPK + k];
        u16x4 v = *reinterpret_cast<const u16x4*>(y + (size_t)p*HID + c);
        o.x += b2f(v[0]); o.y += b2f(v[1]); o.z += b2f(v[2]); o.w += b2f(v[3]);
    }
    *reinterpret_cast<float4*>(out + (size_t)t*HID + c) = o;
}

extern "C" void kernel_launch(void* const* d_in, const int* in_sizes, int n_in,
                              void* d_out, int out_size, void* d_ws, size_t ws_size,
                              hipStream_t stream)
{
    const float* x   = (const float*)d_in[0];
    const float* gw  = (const float*)d_in[1];
    const float* w1  = (const float*)d_in[2];
    const float* w2  = (const float*)d_in[3];
    const float* sgu = (const float*)d_in[4];
    const float* sdn = (const float*)d_in[5];
    float* out = (float*)d_out;

    char* p = (char*)d_ws;
    auto carve = [&](size_t bytes) { char* r = p; p += (bytes + 255) & ~(size_t)255; return r; };
    u16*   xb      = (u16*)  carve((size_t)M_TOK * HID * 2);
    u16*   h       = (u16*)  carve((size_t)TOTSLOT * 1024 * 2);
    u16*   hs      = (u16*)  carve((size_t)M_TOK * 2048 * 2);
    u16*   y       = (u16*)  carve((size_t)TOTSLOT * HID * 2);
    float* gwT     = (float*)carve((size_t)HID * NEXP * 4);
    int*   topk_id = (int*)  carve(M_TOK * TOPK * 4);
    float* topk_w  = (float*)carve(M_TOK * TOPK * 4);
    int*   counts  = (int*)  carve(NEXP * 4);
    int*   offs    = (int*)  carve((NEXP + 1) * 4);
    int*   cursor  = (int*)  carve(NEXP * 4);
    int*   stok    = (int*)  carve(TOTSLOT * 4);
    float* sw      = (float*)carve(TOTSLOT * 4);
    int*   spos    = (int*)  carve(TOTSLOT * 4);

    hipMemsetAsync(counts, 0, NEXP * 4, stream);
    prep_kernel<<<2304, 256, 0, stream>>>(x, xb, gw, gwT);
    router_kernel<<<M_TOK, 64, 0, stream>>>(x, gwT, topk_id, topk_w, counts);
    scan_kernel<<<1, 64, 0, stream>>>(counts, offs, cursor);
    fill_kernel<<<(TOTSLOT + 255)/256, 256, 0, stream>>>(topk_id, topk_w, cursor, stok, sw, spos);

    gemm01_kernel<<<2304, 512, 0, stream>>>(xb, w1, sgu, h, hs, offs, stok, sw);
    gemm23_kernel<<<1280, 512, 0, stream>>>(h, hs, w2, sdn, y, out, offs, stok, sw);
    reduce_kernel<<<M_TOK, 256, 0, stream>>>(y, spos, out);
}

// Round 14
// 466.837 us; speedup vs baseline: 1.4999x; 1.2347x over previous
//
#include <hip/hip_runtime.h>
#include <stdint.h>

#define M_TOK 2048
#define HID   1024
#define NEXP  64
#define TOPK  6
#define TOTSLOT (M_TOK*TOPK)   // 12288

typedef unsigned short u16;
typedef __attribute__((ext_vector_type(4))) u16   u16x4;
typedef __attribute__((ext_vector_type(8))) u16   u16x8;
typedef __attribute__((ext_vector_type(4))) float f32x4;
typedef __attribute__((ext_vector_type(8))) short bf16x8;

__device__ __forceinline__ u16 f2b(float f) {
    union { float f; uint32_t u; } v; v.f = f;
    uint32_t r = v.u + 0x7FFFu + ((v.u >> 16) & 1u);
    return (u16)(r >> 16);
}
__device__ __forceinline__ float b2f(u16 b) {
    union { uint32_t u; float f; } v; v.u = ((uint32_t)b) << 16; return v.f;
}

// ---------------- prep: x fp32->bf16 (blocks 0..2047) + gw transpose (2048..2303) ----
__global__ __launch_bounds__(256) void prep_kernel(const float* __restrict__ x,
                                                   u16* __restrict__ xb,
                                                   const float* __restrict__ gw,
                                                   float* __restrict__ gwT) {
    int b = blockIdx.x;
    if (b < 2048) {
        int i = (b * 256 + threadIdx.x) * 4;
        float4 v = *reinterpret_cast<const float4*>(x + i);
        u16x4 o; o[0] = f2b(v.x); o[1] = f2b(v.y); o[2] = f2b(v.z); o[3] = f2b(v.w);
        *reinterpret_cast<u16x4*>(xb + i) = o;
    } else {
        int i = (b - 2048) * 256 + threadIdx.x;   // 65536 elements
        int e = i >> 10, k = i & 1023;
        gwT[k * NEXP + e] = gw[i];
    }
}

// ---------------- router: fp64 logits (coalesced gwT), grouped topk ----------------
__global__ __launch_bounds__(64) void router_kernel(
    const float* __restrict__ x, const float* __restrict__ gwT,
    int* __restrict__ topk_id, float* __restrict__ topk_w, int* __restrict__ counts)
{
    int t = blockIdx.x, lane = threadIdx.x;
    __shared__ float xr[HID];
    for (int k = lane; k < HID; k += 64) xr[k] = x[(size_t)t * HID + k];
    __syncthreads();
    double s0 = 0.0, s1 = 0.0, s2 = 0.0, s3 = 0.0;
    for (int k = 0; k < HID; k += 4) {
        s0 += (double)xr[k]   * (double)gwT[(k)   * NEXP + lane];
        s1 += (double)xr[k+1] * (double)gwT[(k+1) * NEXP + lane];
        s2 += (double)xr[k+2] * (double)gwT[(k+2) * NEXP + lane];
        s3 += (double)xr[k+3] * (double)gwT[(k+3) * NEXP + lane];
    }
    double s = (s0 + s1) + (s2 + s3);
    __shared__ double lg[NEXP];
    __shared__ float  pr[NEXP];
    float sf = (float)s;
    float mx = sf;
    for (int o = 32; o; o >>= 1) mx = fmaxf(mx, __shfl_xor(mx, o));
    float ev = __expf(sf - mx);
    float sum = ev;
    for (int o = 32; o; o >>= 1) sum += __shfl_xor(sum, o);
    lg[lane] = s; pr[lane] = ev / sum;
    __syncthreads();
    if (lane == 0) {
        double gs[8];
        #pragma unroll
        for (int g = 0; g < 8; ++g) {
            double m = lg[g*8];
            #pragma unroll
            for (int i = 1; i < 8; ++i) m = fmax(m, lg[g*8+i]);
            gs[g] = m;
        }
        unsigned gsel = 0;
        for (int r = 0; r < 3; ++r) {
            int bi = 0; double bv = -1e300;
            for (int g = 0; g < 8; ++g)
                if (!((gsel>>g)&1u) && gs[g] > bv) { bv = gs[g]; bi = g; }
            gsel |= 1u << bi;
        }
        unsigned long long taken = 0;
        for (int r = 0; r < TOPK; ++r) {
            int bi = 0; double bv = -1e300;
            for (int e = 0; e < NEXP; ++e) {
                if (!((gsel >> (e>>3)) & 1u)) continue;
                if ((taken >> e) & 1ull) continue;
                if (lg[e] > bv) { bv = lg[e]; bi = e; }
            }
            taken |= 1ull << bi;
            topk_id[t*TOPK + r] = bi;
            topk_w[t*TOPK + r] = pr[bi];
            atomicAdd(&counts[bi], 1);
        }
    }
}

__global__ void scan_kernel(const int* __restrict__ counts, int* __restrict__ offs,
                            int* __restrict__ cursor) {
    if (threadIdx.x == 0) {
        int acc = 0;
        for (int e = 0; e < NEXP; ++e) { offs[e] = acc; cursor[e] = acc; acc += counts[e]; }
        offs[NEXP] = acc;
    }
}

__global__ __launch_bounds__(256) void fill_kernel(
    const int* __restrict__ topk_id, const float* __restrict__ topk_w,
    int* __restrict__ cursor, int* __restrict__ stok, float* __restrict__ sw,
    int* __restrict__ spos)
{
    int idx = blockIdx.x*256 + threadIdx.x;
    if (idx >= TOTSLOT) return;
    int e = topk_id[idx];
    int pos = atomicAdd(&cursor[e], 1);
    stok[pos] = idx / TOPK;
    sw[pos] = topk_w[idx];
    spos[idx] = pos;
}

// ---------------- GEMM core: BM=128, BN=128, BK=64, 512 thr, 2 blocks/CU ----------------
// KIND 0: routed gate/up  A=xb[tok] K=1024, B=w1[e] -> h (silu*up*w, bf16)
// KIND 1: shared gate/up  A=xb      K=1024, B=sgu  -> hs (bf16)
// KIND 2: routed down     A=h       K=1024, B=w2[e]-> y  (bf16)
// KIND 3: shared down     A=hs      K=2048, B=sdn  -> Out (f32)
// BK=64: each staged B row-slice is 256B contiguous fp32 (2x DRAM burst length vs BK=32)
// and barrier count halves. LDS row = 128B = 8 chunks of 16B, chunk stored at
// (chunk ^ (row&7)) -- same involution on write (storeB / pre-swizzled A source) and
// read (mfma_phase). 8 waves x 16 M-rows, MR=1, acc[8]=32 regs.
template<int KIND>
__device__ __forceinline__ void gemm_core(
    const int e, const int my, const int nblk,
    const u16* __restrict__ A, const float* __restrict__ Bw,
    u16* __restrict__ Hout, float* __restrict__ Out,
    const int* __restrict__ offs, const int* __restrict__ stok,
    const float* __restrict__ sw,
    u16* __restrict__ AsR, u16* __restrict__ BsR,
    int* __restrict__ tkl, float* __restrict__ swl)
{
    constexpr bool G1     = (KIND == 0 || KIND == 1);
    constexpr bool ROUTED = (KIND == 0 || KIND == 2);
    constexpr int  BM     = 128;
    constexpr int  KD     = (KIND == 3) ? 2048 : 1024;
    constexpr int  KITER  = KD / 64;
    constexpr int  NPAIR  = (KIND == 0) ? 1024 : 2048;

    const int tid  = threadIdx.x;
    const int lane = tid & 63;
    const int wv   = tid >> 6;

    int off = 0, cnt = M_TOK;
    if (ROUTED) { off = offs[e]; cnt = offs[e+1] - off; }
    const int m0 = my * BM;
    if (m0 >= cnt) return;

    if (ROUTED && tid < BM) {
        int gr = m0 + tid;
        if (KIND == 0) {
            tkl[tid] = (gr < cnt) ? stok[off + gr] : 0;
            swl[tid] = (gr < cnt) ? sw[off + gr] : 0.f;
        } else {
            int r = off + gr; if (r > TOTSLOT-1) r = TOTSLOT-1;
            tkl[tid] = r;
        }
    }
    __syncthreads();

    // A staging: wave stages 8 rows/call (64 lanes x 16B = 1KB = 8 rows x 128B), 2 calls.
    // lane -> row_off = lane>>3, chunk c = lane&7; linear dest = base + lane*16.
    // Source pre-swizzle: stored chunk c holds source chunk c ^ (row&7); row&7 = lane>>3.
    const int acol8 = (lane & 7) ^ (lane >> 3);
    int aoff[2];
    #pragma unroll
    for (int j = 0; j < 2; ++j) {
        int r = wv*16 + j*8 + (lane >> 3);
        int arow = ROUTED ? tkl[r] : (m0 + r);
        aoff[j] = arow * KD + acol8 * 8;
    }

    const float* Be = Bw;
    if (KIND == 0) Be += (size_t)e * (size_t)(2*1024*1024);
    if (KIND == 2) Be += (size_t)e * (size_t)(1024*1024);
    // B staging: 128 rows x 64 fp32; 4 threads/row, 16 fp32 (64B) contiguous per thread.
    const int rb = tid >> 2;
    const int q  = tid & 3;
    int brow;
    if (G1) brow = (rb < 64) ? (nblk*64 + rb) : (NPAIR + nblk*64 + (rb - 64));
    else    brow = nblk*128 + rb;
    const float* bsrc = Be + (size_t)brow * KD + q*16;

    float4 br[4];

    auto stageA = [&](int buf, int k0) {
        #pragma unroll
        for (int j = 0; j < 2; ++j) {
            __builtin_amdgcn_global_load_lds(
                (const __attribute__((address_space(1))) uint32_t*)(A + (size_t)(aoff[j] + k0)),
                (__attribute__((address_space(3))) uint32_t*)(AsR + buf*(BM*64) + (wv*16 + j*8)*64),
                16, 0, 0);
        }
    };
    auto loadB = [&](int k0) {
        #pragma unroll
        for (int j = 0; j < 4; ++j)
            br[j] = *reinterpret_cast<const float4*>(bsrc + k0 + j*4);
    };
    auto storeB = [&](int buf) {
        char* bd = (char*)(BsR + buf*(128*64)) + rb*128;
        #pragma unroll
        for (int half = 0; half < 2; ++half) {
            u16x8 w;
            w[0] = f2b(br[2*half].x);   w[1] = f2b(br[2*half].y);
            w[2] = f2b(br[2*half].z);   w[3] = f2b(br[2*half].w);
            w[4] = f2b(br[2*half+1].x); w[5] = f2b(br[2*half+1].y);
            w[6] = f2b(br[2*half+1].z); w[7] = f2b(br[2*half+1].w);
            int ch = q*2 + half;
            *reinterpret_cast<u16x8*>(bd + ((ch ^ (rb & 7)) << 4)) = w;
        }
    };

    f32x4 acc[8];
    #pragma unroll
    for (int nf = 0; nf < 8; ++nf) acc[nf] = (f32x4){0.f, 0.f, 0.f, 0.f};

    auto mfma_phase = [&](int buf) {
        const char* Ab = (const char*)(AsR + buf*(BM*64));
        const char* Bb = (const char*)(BsR + buf*(128*64));
        #pragma unroll
        for (int kk = 0; kk < 2; ++kk) {
            const int sc = kk*4 + (lane >> 4);
            const int ra = wv*16 + (lane & 15);
            bf16x8 af = *reinterpret_cast<const bf16x8*>(Ab + ra*128 + ((sc ^ (ra & 7)) << 4));
            #pragma unroll
            for (int nf = 0; nf < 8; ++nf) {
                int rbb = nf*16 + (lane & 15);
                bf16x8 bfr = *reinterpret_cast<const bf16x8*>(Bb + rbb*128 + ((sc ^ (rbb & 7)) << 4));
                acc[nf] = __builtin_amdgcn_mfma_f32_16x16x32_bf16(af, bfr, acc[nf], 0, 0, 0);
            }
        }
    };

    stageA(0, 0);
    loadB(0);
    storeB(0);
    __syncthreads();

    for (int kt = 0; kt < KITER; ++kt) {
        const int cur = kt & 1, nxt = cur ^ 1;
        const bool more = (kt + 1 < KITER);
        if (more) { stageA(nxt, (kt + 1) * 64); loadB((kt + 1) * 64); }
        mfma_phase(cur);
        if (more) storeB(nxt);
        __syncthreads();
    }

    if constexpr (G1) {
        const int colbase = nblk*64 + (lane & 15);
        #pragma unroll
        for (int j = 0; j < 4; ++j) {
            int r = wv*16 + (lane >> 4)*4 + j;
            if (ROUTED && (m0 + r) >= cnt) continue;
            float wgt = (KIND == 0) ? swl[r] : 1.0f;
            size_t orow = (size_t)(ROUTED ? (off + m0 + r) : (m0 + r));
            #pragma unroll
            for (int nf = 0; nf < 4; ++nf) {
                float g = acc[nf][j];
                float u = acc[nf+4][j];
                float hv = (g / (1.f + __expf(-g))) * u * wgt;
                Hout[orow * NPAIR + colbase + nf*16] = f2b(hv);
            }
        }
    } else {
        const int colbase = nblk*128 + (lane & 15);
        #pragma unroll
        for (int j = 0; j < 4; ++j) {
            int r = wv*16 + (lane >> 4)*4 + j;
            if (ROUTED && (m0 + r) >= cnt) continue;
            #pragma unroll
            for (int nf = 0; nf < 8; ++nf) {
                float v = acc[nf][j];
                if (KIND == 2) Hout[(size_t)(off + m0 + r) * HID + colbase + nf*16] = f2b(v);
                else           Out[(size_t)(m0 + r) * HID + colbase + nf*16] = v;
            }
        }
    }
}

// ---- fused launch 1: routed gate/up (0..2047) + shared gate/up (2048..2559) ----
__global__ __launch_bounds__(512, 4) void gemm01_kernel(
    const u16* __restrict__ xb, const float* __restrict__ w1, const float* __restrict__ sgu,
    u16* __restrict__ h, u16* __restrict__ hs,
    const int* __restrict__ offs, const int* __restrict__ stok, const float* __restrict__ sw)
{
    __shared__ u16 AsR[2*128*64];
    __shared__ u16 BsR[2*128*64];
    __shared__ int   tkl[128];
    __shared__ float swl[128];
    const int rid = blockIdx.x;
    if (rid < 2048) {           // 8 experts/XCD, 32 blocks/expert (my 0..1, nblk 0..15)
        int slot = rid >> 3;
        int e = (rid & 7) * 8 + (slot >> 5);
        int sub = slot & 31;
        gemm_core<0>(e, sub >> 4, sub & 15, xb, w1, h, nullptr, offs, stok, sw, AsR, BsR, tkl, swl);
    } else {                    // shared gate/up: 512 blocks (my 0..15, nblk 0..31)
        int sid = rid - 2048;
        int slot = sid >> 3;
        gemm_core<1>(0, slot & 15, (sid & 7) * 4 + (slot >> 4), xb, sgu, hs, nullptr,
                     offs, stok, sw, AsR, BsR, tkl, swl);
    }
}

// ---- fused launch 2: shared down (0..127, K=2048, longest-first) + routed down ----
__global__ __launch_bounds__(512, 4) void gemm23_kernel(
    const u16* __restrict__ h, const u16* __restrict__ hs,
    const float* __restrict__ w2, const float* __restrict__ sdn,
    u16* __restrict__ y, float* __restrict__ out,
    const int* __restrict__ offs, const int* __restrict__ stok, const float* __restrict__ sw)
{
    __shared__ u16 AsR[2*128*64];
    __shared__ u16 BsR[2*128*64];
    __shared__ int   tkl[128];
    __shared__ float swl[128];
    const int rid = blockIdx.x;
    if (rid >= 128) {           // routed down: 1024 blocks, 8 experts/XCD (my 0..1, nblk 0..7)
        int r2 = rid - 128;
        int slot = r2 >> 3;
        int e = (r2 & 7) * 8 + (slot >> 4);
        int sub = slot & 15;
        gemm_core<2>(e, sub >> 3, sub & 7, h, w2, y, nullptr, offs, stok, sw, AsR, BsR, tkl, swl);
    } else {                    // shared down: 128 blocks (my 0..15, nblk 0..7)
        int slot = rid >> 3;
        gemm_core<3>(0, slot, rid & 7, hs, sdn, nullptr, out,
                     offs, stok, sw, AsR, BsR, tkl, swl);
    }
}

// ---------------- gather-reduce: out[t] += sum_k y[spos[t,k]] ----------------
__global__ __launch_bounds__(256) void reduce_kernel(
    const u16* __restrict__ y, const int* __restrict__ spos, float* __restrict__ out)
{
    int t = blockIdx.x;
    int c = threadIdx.x * 4;
    float4 o = *reinterpret_cast<const float4*>(out + (size_t)t*HID + c);
    #pragma unroll
    for (int k = 0; k < TOPK; ++k) {
        int p = spos[t*TOPK + k];
        u16x4 v = *reinterpret_cast<const u16x4*>(y + (size_t)p*HID + c);
        o.x += b2f(v[0]); o.y += b2f(v[1]); o.z += b2f(v[2]); o.w += b2f(v[3]);
    }
    *reinterpret_cast<float4*>(out + (size_t)t*HID + c) = o;
}

extern "C" void kernel_launch(void* const* d_in, const int* in_sizes, int n_in,
                              void* d_out, int out_size, void* d_ws, size_t ws_size,
                              hipStream_t stream)
{
    const float* x   = (const float*)d_in[0];
    const float* gw  = (const float*)d_in[1];
    const float* w1  = (const float*)d_in[2];
    const float* w2  = (const float*)d_in[3];
    const float* sgu = (const float*)d_in[4];
    const float* sdn = (const float*)d_in[5];
    float* out = (float*)d_out;

    char* p = (char*)d_ws;
    auto carve = [&](size_t bytes) { char* r = p; p += (bytes + 255) & ~(size_t)255; return r; };
    u16*   xb      = (u16*)  carve((size_t)M_TOK * HID * 2);
    u16*   h       = (u16*)  carve((size_t)TOTSLOT * 1024 * 2);
    u16*   hs      = (u16*)  carve((size_t)M_TOK * 2048 * 2);
    u16*   y       = (u16*)  carve((size_t)TOTSLOT * HID * 2);
    float* gwT     = (float*)carve((size_t)HID * NEXP * 4);
    int*   topk_id = (int*)  carve(M_TOK * TOPK * 4);
    float* topk_w  = (float*)carve(M_TOK * TOPK * 4);
    int*   counts  = (int*)  carve(NEXP * 4);
    int*   offs    = (int*)  carve((NEXP + 1) * 4);
    int*   cursor  = (int*)  carve(NEXP * 4);
    int*   stok    = (int*)  carve(TOTSLOT * 4);
    float* sw      = (float*)carve(TOTSLOT * 4);
    int*   spos    = (int*)  carve(TOTSLOT * 4);

    hipMemsetAsync(counts, 0, NEXP * 4, stream);
    prep_kernel<<<2304, 256, 0, stream>>>(x, xb, gw, gwT);
    router_kernel<<<M_TOK, 64, 0, stream>>>(x, gwT, topk_id, topk_w, counts);
    scan_kernel<<<1, 64, 0, stream>>>(counts, offs, cursor);
    fill_kernel<<<(TOTSLOT + 255)/256, 256, 0, stream>>>(topk_id, topk_w, cursor, stok, sw, spos);

    gemm01_kernel<<<2560, 512, 0, stream>>>(xb, w1, sgu, h, hs, offs, stok, sw);
    gemm23_kernel<<<1152, 512, 0, stream>>>(h, hs, w2, sdn, y, out, offs, stok, sw);
    reduce_kernel<<<M_TOK, 256, 0, stream>>>(y, spos, out);
}